// Round 6
// baseline (10151.251 us; speedup 1.0000x reference)
//
#include <hip/hip_runtime.h>
#include <hip/hip_bf16.h>
#include <type_traits>

#define B_   64
#define T_   48
#define H_   512
#define E_   512
#define ATT_ 196
#define AF_  2048
#define FC_  2048
#define V_   10000

typedef unsigned short u16;
typedef unsigned int u32;
typedef unsigned long long u64;
using s16x8 = __attribute__((ext_vector_type(8))) short;
using f32x4 = __attribute__((ext_vector_type(4))) float;

// input-storage modes for GEMM/pointwise loaders
#define MD_BF16 0
#define MD_F32  1
#define MD_DYN  2   // resolve from detected flag (d_in float tensors)

__device__ __forceinline__ float b2f(u16 u) {
  union { unsigned int i; float f; } x; x.i = ((unsigned int)u) << 16; return x.f;
}
__device__ __forceinline__ u16 f2b(float f) {
  union { float f; unsigned int i; } x; x.f = f;
  unsigned int r = x.i + 0x7fffu + ((x.i >> 16) & 1u);
  return (u16)(r >> 16);
}
__device__ __forceinline__ float sigmoid_(float x) { return 1.f / (1.f + __expf(-x)); }
__device__ __forceinline__ float tanh_(float x) { return 1.f - 2.f / (__expf(2.f * x) + 1.f); }

__device__ __forceinline__ float ldf(const void* p, size_t i, int f) {
  return f ? ((const float*)p)[i] : b2f(((const u16*)p)[i]);
}
__device__ __forceinline__ s16x8 ld8(const void* p, size_t idx, int f) {
  s16x8 r;
  if (f) {
    const float* q = (const float*)p + idx;
    float4 x = *(const float4*)q;
    float4 y = *(const float4*)(q + 4);
    r[0] = (short)f2b(x.x); r[1] = (short)f2b(x.y);
    r[2] = (short)f2b(x.z); r[3] = (short)f2b(x.w);
    r[4] = (short)f2b(y.x); r[5] = (short)f2b(y.y);
    r[6] = (short)f2b(y.z); r[7] = (short)f2b(y.w);
  } else {
    r = *(const s16x8*)((const u16*)p + idx);
  }
  return r;
}
__device__ __forceinline__ s16x8 zero8() {
  s16x8 r; for (int j = 0; j < 8; j++) r[j] = 0; return r;
}

// storage detector: f32 storage => u16 view of att_feats contains exponent-0xFF
// bit patterns (random mantissa halves) with certainty; bf16 N(0,1) never does.
__global__ void detect_f32(const u16* __restrict__ p, int* __restrict__ flag) {
  __shared__ int sb[256];
  int t = threadIdx.x, bad = 0;
  for (int i = t; i < 65536; i += 256) {
    int e = (p[i] >> 7) & 0xFF;
    bad |= (e == 0xFF) ? 1 : 0;
  }
  sb[t] = bad; __syncthreads();
  for (int s = 128; s; s >>= 1) { if (t < s) sb[t] |= sb[t + s]; __syncthreads(); }
  if (t == 0) *flag = sb[0];
}

// ---------------------------------------------------------------------------
// NT GEMM (one-time GEMMs): C[MxN] = A[MxK] * B[NxK]^T (+bias), bf16 MFMA.
// ---------------------------------------------------------------------------
template <typename CT>
__global__ __launch_bounds__(256) void gemm_nt(
    const void* __restrict__ A, int lda, size_t aoff, int amode,
    const void* __restrict__ B, int ldb, size_t boff, int bmode,
    CT* __restrict__ C, int ldc, int N, int Kc,
    const float* __restrict__ bias, size_t zstride, const int* __restrict__ flagp)
{
  __shared__ __align__(16) u16 As[64 * 40];
  __shared__ __align__(16) u16 Bs[64 * 40];

  const int dynf = *flagp;
  const int aF = (amode == MD_DYN) ? dynf : amode;
  const int bF = (bmode == MD_DYN) ? dynf : bmode;

  const int tid  = threadIdx.x;
  const int m0   = blockIdx.x * 64;
  const int n0   = blockIdx.y * 64;
  const int kz   = blockIdx.z * Kc;
  const int lane = tid & 63;
  const int w    = tid >> 6;
  const int wm   = (w >> 1) * 32;
  const int wn   = (w & 1) * 32;
  const int quad = lane >> 4;
  const int r16  = lane & 15;

  f32x4 acc[2][2];
  for (int a = 0; a < 2; a++) for (int b = 0; b < 2; b++)
    for (int k = 0; k < 4; k++) acc[a][b][k] = 0.f;

  const int sr = tid >> 2;
  const int sc = (tid & 3) * 8;
  const size_t idxA = (size_t)(m0 + sr) * lda + aoff + kz + sc;
  const size_t idxB = (size_t)(n0 + sr) * ldb + boff + kz + sc;
  const bool bok = (n0 + sr) < N;

  const int aoff0 = (wm + r16) * 40 + quad * 8;
  const int aoff1 = (wm + 16 + r16) * 40 + quad * 8;
  const int boff0 = (wn + r16) * 40 + quad * 8;
  const int boff1 = (wn + 16 + r16) * 40 + quad * 8;

  s16x8 av = ld8(A, idxA, aF);
  s16x8 bv = bok ? ld8(B, idxB, bF) : zero8();

  for (int k0 = 0; k0 < Kc; k0 += 32) {
    s16x8 avn = zero8(), bvn = zero8();
    if (k0 + 32 < Kc) {
      avn = ld8(A, idxA + k0 + 32, aF);
      if (bok) bvn = ld8(B, idxB + k0 + 32, bF);
    }
    __syncthreads();
    *(s16x8*)(As + sr * 40 + sc) = av;
    *(s16x8*)(Bs + sr * 40 + sc) = bv;
    __syncthreads();
    s16x8 a0 = *(const s16x8*)(As + aoff0);
    s16x8 a1 = *(const s16x8*)(As + aoff1);
    s16x8 b0 = *(const s16x8*)(Bs + boff0);
    s16x8 b1 = *(const s16x8*)(Bs + boff1);
    acc[0][0] = __builtin_amdgcn_mfma_f32_16x16x32_bf16(a0, b0, acc[0][0], 0, 0, 0);
    acc[0][1] = __builtin_amdgcn_mfma_f32_16x16x32_bf16(a0, b1, acc[0][1], 0, 0, 0);
    acc[1][0] = __builtin_amdgcn_mfma_f32_16x16x32_bf16(a1, b0, acc[1][0], 0, 0, 0);
    acc[1][1] = __builtin_amdgcn_mfma_f32_16x16x32_bf16(a1, b1, acc[1][1], 0, 0, 0);
    av = avn; bv = bvn;
  }

  CT* Cz = C + (size_t)blockIdx.z * zstride;
  const bool addb = (bias != nullptr) && (blockIdx.z == 0);
  for (int tm = 0; tm < 2; tm++)
    for (int tn = 0; tn < 2; tn++) {
      int col = n0 + wn + tn * 16 + r16;
      if (col >= N) continue;
      float bb = addb ? bias[col] : 0.f;
      int rowbase = m0 + wm + tm * 16 + quad * 4;
      for (int rg = 0; rg < 4; rg++) {
        float v = acc[tm][tn][rg] + bb;
        if constexpr (std::is_same<CT, float>::value)
          Cz[(size_t)(rowbase + rg) * ldc + col] = v;
        else
          Cz[(size_t)(rowbase + rg) * ldc + col] = f2b(v);
      }
    }
}

// ---------------------------------------------------------------------------
// PER-BATCH recurrence kernel: 64 blocks x 512 threads, ONE block per batch,
// zero grid sync. The entire h/c history lives in LDS (48x512 bf16 + 48x512
// f32 = 144 KB); weights stream from L2 (shared by the 8 blocks per XCD).
// Per step i (thread j owns element j):
//   stage hs = [h[father] | h_f] (LDS bf16)
//   tatf GEMV (VALU)  -> tat[j]
//   logits (wave-split tanh dots over p_att) -> softmax -> apply -> attc (reg)
//   gates-h GEMV via MFMA (1-valid-row A frag) -> Gout[2560] (LDS)
//   finish: gates = Gout + Gx + bias -> nh, nc -> LDS history + houts
// Gout[2560] also hosts tat/sl/red scratch (disjoint phases, sync-separated).
// ---------------------------------------------------------------------------
__global__ __launch_bounds__(512) void batch_loop(
    const u16* __restrict__ WstepH, const float* __restrict__ biasStep,
    const float* __restrict__ Gx,
    const u16* __restrict__ Whahf, const float* __restrict__ bhahf,
    const u16* __restrict__ p_att, const float* __restrict__ walpha_f,
    const u16* __restrict__ att_proj, const float* __restrict__ att_meanp,
    u16* __restrict__ houts, const int* __restrict__ father_idx)
{
  __shared__ __align__(16) u16  h_hist[T_ * H_];   // 49152 B
  __shared__ __align__(16) float c_hist[T_ * H_];  // 98304 B
  __shared__ __align__(16) u16  hs_bf[1024];       //  2048 B
  __shared__ __align__(16) float Gout[2560];       // 10240 B (also tat/sl/red)
  float* tatp = Gout;          // [0, 512)
  float* slp  = Gout + 512;    // [512, 768)   (196 used)
  float* redp = Gout + 1024;   // [1024, 1536)

  const int b    = blockIdx.x;
  const int tid  = threadIdx.x;
  const int lane = tid & 63;
  const int w    = tid >> 6;
  const int r16  = lane & 15;
  const int quad = lane >> 4;

  // zero-init history (covers father>=i reads of "future" state)
  for (int idx = tid; idx < T_ * H_ / 2; idx += 512) ((u32*)h_hist)[idx] = 0u;
  for (int idx = tid; idx < T_ * H_; idx += 512) c_hist[idx] = 0.f;

  // hoisted per-thread constants
  const float bias0 = biasStep[tid];
  const float bias1 = biasStep[512 + tid];
  const float bias2 = biasStep[1024 + tid];
  const float bias3 = biasStep[1536 + tid];
  const float bias4 = biasStep[2048 + tid];
  const float bh    = bhahf[tid];
  const float attm  = att_meanp[b * H_ + tid];
  float wa8[8];
#pragma unroll
  for (int j = 0; j < 8; j++) wa8[j] = walpha_f[lane * 8 + j];
  __syncthreads();

  for (int i = 0; i < T_; ++i) {
    const int father = father_idx[b * T_ + i];
    const int use_f  = (i > 0) && ((i - 1) % 3 != 0);
    // Gx prefetch (x-half of gates, precomputed; streamed, coalesced)
    const float* gxp = Gx + ((size_t)i * B_ + b) * 2560 + tid;
    const float gx0 = gxp[0],    gx1 = gxp[512],  gx2 = gxp[1024];
    const float gx3 = gxp[1536], gx4 = gxp[2048];

    float attc_r = attm;
    float g0 = 0.f, g1 = 0.f, g2 = 0.f, g3 = 0.f, g4 = 0.f;

    if (i > 0) {
      // ---- stage h_cat = [h_a | h_f] ----
      hs_bf[tid]       = h_hist[father * H_ + tid];
      hs_bf[512 + tid] = use_f ? h_hist[(i - 1) * H_ + tid] : (u16)0;
      __syncthreads();

      // ---- tatf[j] = dot(Whahf[j,:], hs) + (b_ha+b_hf)[j] ----
      {
        const u16* wr = Whahf + (size_t)tid * 1024;
        float a0 = 0.f, a1 = 0.f, a2 = 0.f, a3 = 0.f;
#pragma unroll 4
        for (int k0 = 0; k0 < 1024; k0 += 8) {
          s16x8 w8 = *(const s16x8*)(wr + k0);
          s16x8 h8 = *(const s16x8*)(hs_bf + k0);
          a0 += b2f((u16)w8[0]) * b2f((u16)h8[0]);
          a1 += b2f((u16)w8[1]) * b2f((u16)h8[1]);
          a2 += b2f((u16)w8[2]) * b2f((u16)h8[2]);
          a3 += b2f((u16)w8[3]) * b2f((u16)h8[3]);
          a0 += b2f((u16)w8[4]) * b2f((u16)h8[4]);
          a1 += b2f((u16)w8[5]) * b2f((u16)h8[5]);
          a2 += b2f((u16)w8[6]) * b2f((u16)h8[6]);
          a3 += b2f((u16)w8[7]) * b2f((u16)h8[7]);
        }
        tatp[tid] = (a0 + a1) + (a2 + a3) + bh;
      }
      __syncthreads();

      // ---- logits: wave w -> a = w, w+8, ...; 1-deep p_att prefetch ----
      {
        float t8[8];
#pragma unroll
        for (int j = 0; j < 8; j++) t8[j] = tatp[lane * 8 + j];
        const u16* pb = p_att + (size_t)b * ATT_ * 512 + lane * 8;
        s16x8 pv = *(const s16x8*)(pb + (size_t)w * 512);
        for (int a = w; a < ATT_; a += 8) {
          s16x8 nx = zero8();
          if (a + 8 < ATT_) nx = *(const s16x8*)(pb + (size_t)(a + 8) * 512);
          float acc = 0.f;
#pragma unroll
          for (int j = 0; j < 8; j++)
            acc += wa8[j] * tanh_(t8[j] + b2f((u16)pv[j]));
#pragma unroll
          for (int off = 32; off; off >>= 1) acc += __shfl_down(acc, off);
          if (lane == 0) slp[a] = acc;
          pv = nx;
        }
      }
      __syncthreads();

      // ---- softmax over 196 logits ----
      {
        float l = (tid < ATT_) ? slp[tid] : -3.0e38f;
        redp[tid] = l; __syncthreads();
        for (int s = 256; s; s >>= 1) { if (tid < s) redp[tid] = fmaxf(redp[tid], redp[tid + s]); __syncthreads(); }
        float mx = redp[0]; __syncthreads();
        float e = (tid < ATT_) ? __expf(l - mx) : 0.f;
        redp[tid] = e; __syncthreads();
        for (int s = 256; s; s >>= 1) { if (tid < s) redp[tid] += redp[tid + s]; __syncthreads(); }
        float inv = 1.f / redp[0];
        __syncthreads();
        if (tid < ATT_) slp[tid] = e * inv;
      }
      __syncthreads();

      // ---- apply: attc[j] = sum_a w[a] * att_proj[b,a,j] (thread-local) ----
      {
        const u16* ap = att_proj + (size_t)b * ATT_ * 512 + tid;
        float ac0 = 0.f, ac1 = 0.f, ac2 = 0.f, ac3 = 0.f;
        for (int a = 0; a < ATT_; a += 4) {
          ac0 += slp[a]     * b2f(ap[(size_t)a * 512]);
          ac1 += slp[a + 1] * b2f(ap[(size_t)(a + 1) * 512]);
          ac2 += slp[a + 2] * b2f(ap[(size_t)(a + 2) * 512]);
          ac3 += slp[a + 3] * b2f(ap[(size_t)(a + 3) * 512]);
        }
        attc_r = (ac0 + ac1) + (ac2 + ac3);
      }
      __syncthreads();   // tat/sl/red reads done before Gout is overwritten

      // ---- gates-h GEMV via MFMA: n = w*320 + cc*80 + g*16 + r16 ----
      // A-frag: row r16 (only row 0 valid = h vector), k-chunk quad*8.
      // C row 0 lands in lanes 0..15, acc element [0] (layout as gemm_nt).
#pragma unroll
      for (int cc = 0; cc < 4; ++cc) {
        f32x4 acc[5];
#pragma unroll
        for (int g = 0; g < 5; g++)
#pragma unroll
          for (int k = 0; k < 4; k++) acc[g][k] = 0.f;
        const u16* bp = WstepH + (size_t)(w * 320 + cc * 80 + r16) * 1024 + quad * 8;
#pragma unroll 4
        for (int ks = 0; ks < 32; ++ks) {
          s16x8 af = zero8();
          if (r16 == 0) af = *(const s16x8*)(hs_bf + ks * 32 + quad * 8);
          const int ko = ks * 32;
          acc[0] = __builtin_amdgcn_mfma_f32_16x16x32_bf16(af, *(const s16x8*)(bp + ko), acc[0], 0, 0, 0);
          acc[1] = __builtin_amdgcn_mfma_f32_16x16x32_bf16(af, *(const s16x8*)(bp + 16 * 1024 + ko), acc[1], 0, 0, 0);
          acc[2] = __builtin_amdgcn_mfma_f32_16x16x32_bf16(af, *(const s16x8*)(bp + 32 * 1024 + ko), acc[2], 0, 0, 0);
          acc[3] = __builtin_amdgcn_mfma_f32_16x16x32_bf16(af, *(const s16x8*)(bp + 48 * 1024 + ko), acc[3], 0, 0, 0);
          acc[4] = __builtin_amdgcn_mfma_f32_16x16x32_bf16(af, *(const s16x8*)(bp + 64 * 1024 + ko), acc[4], 0, 0, 0);
        }
        if (lane < 16) {
#pragma unroll
          for (int g = 0; g < 5; g++)
            Gout[w * 320 + cc * 80 + g * 16 + lane] = acc[g][0];
        }
      }
      __syncthreads();
      g0 = Gout[tid];        g1 = Gout[512 + tid];  g2 = Gout[1024 + tid];
      g3 = Gout[1536 + tid]; g4 = Gout[2048 + tid];
    }

    // ---- finish (thread j owns element j; no cross-thread hazards) ----
    {
      float ing  = sigmoid_(g0 + gx0 + bias0);
      float outg = sigmoid_(g1 + gx1 + bias1);
      float cg   = tanh_(g2 + gx2 + bias2 + attc_r);
      float f1   = sigmoid_(g3 + gx3 + bias3);
      float f2   = sigmoid_(g4 + gx4 + bias4);
      float c1 = (i > 0) ? c_hist[father * H_ + tid] : 0.f;
      float c2 = use_f ? c_hist[(i - 1) * H_ + tid] : 0.f;
      float nc = f1 * c1 + f2 * c2 + ing * cg;
      float nh = outg * tanh_(nc);
      c_hist[i * H_ + tid] = nc;
      u16 hb = f2b(nh);
      h_hist[i * H_ + tid] = hb;
      houts[((size_t)b * T_ + i) * H_ + tid] = hb;
    }
    __syncthreads();
  }
}

// --- weight/bias packing (reads d_in floats via flag) ------------------------
// Wstep row space (2560 gates rows over cat=[x_a|x_f|h_a|h_f]) split by K:
// WstepX = cols 0..1023 (x part), WstepH = cols 1024..2047 (h part).
__global__ __launch_bounds__(256) void pack_wstep(
    const void* __restrict__ wH, const void* __restrict__ wI,
    const void* __restrict__ wf1, const void* __restrict__ wf2,
    u16* __restrict__ WstepX, u16* __restrict__ WstepH,
    const int* __restrict__ flagp)
{
  const int F = *flagp;
  for (int idx = blockIdx.x * 256 + threadIdx.x; idx < 2560 * 2048; idx += gridDim.x * 256) {
    int row = idx >> 11, col = idx & 2047;
    float v = 0.f;
    if (row < 1024) v = ldf(wH, (size_t)row * 2048 + col, F);
    else if (row < 1536) v = ldf(wI, (size_t)(row - 1024) * 4096 + col, F);
    else if (row < 2048) {
      int r = row - 1536;
      if (col < 512) v = ldf(wf1, (size_t)r * 1024 + col, F);
      else if (col >= 1024 && col < 1536) v = ldf(wf1, (size_t)r * 1024 + 512 + (col - 1024), F);
    } else {
      int r = row - 2048;
      if (col >= 512 && col < 1024) v = ldf(wf2, (size_t)r * 1024 + (col - 512), F);
      else if (col >= 1536) v = ldf(wf2, (size_t)r * 1024 + 512 + (col - 1536), F);
    }
    if (col < 1024) WstepX[(size_t)row * 1024 + col] = f2b(v);
    else           WstepH[(size_t)row * 1024 + (col - 1024)] = f2b(v);
  }
}

__global__ __launch_bounds__(256) void pack_whahf(
    const void* __restrict__ W_ha, const void* __restrict__ W_hf,
    u16* __restrict__ Whahf, const int* __restrict__ flagp)
{
  const int F = *flagp;
  for (int idx = blockIdx.x * 256 + threadIdx.x; idx < 512 * 1024; idx += gridDim.x * 256) {
    int e = idx >> 10, k = idx & 1023;
    float v = (k < 512) ? ldf(W_ha, (size_t)e * 512 + k, F)
                        : ldf(W_hf, (size_t)e * 512 + (k - 512), F);
    Whahf[idx] = f2b(v);
  }
}

// att_feats -> bf16 copy (zero numerical change: GEMMs already cast to bf16)
__global__ __launch_bounds__(256) void pack_attf(
    const void* __restrict__ src, u16* __restrict__ dst, const int* __restrict__ flagp)
{
  const int F = *flagp;
  const size_t n8 = (size_t)B_ * ATT_ * AF_ / 8;
  for (size_t idx = (size_t)blockIdx.x * 256 + threadIdx.x; idx < n8;
       idx += (size_t)gridDim.x * 256) {
    s16x8 v = ld8(src, idx * 8, F);
    *(s16x8*)(dst + idx * 8) = v;
  }
}

// XAll[i*64+b][0..1023] = [x_a | x_f] for step i, batch b (bf16)
__global__ __launch_bounds__(256) void pack_xall(
    const float* __restrict__ fc_emb, const void* __restrict__ embed_tab,
    const int* __restrict__ word_idx, const int* __restrict__ father_idx,
    u16* __restrict__ XAll, const int* __restrict__ flagp)
{
  const int F = *flagp;
  const int ib = blockIdx.x;          // 0..3071
  const int i = ib >> 6, b = ib & 63;
  u16* xr = XAll + (size_t)ib * 1024;
  const int fa = father_idx[b * T_ + i];
  const int wa = word_idx[b * T_ + fa];
  const int use_f = (i > 0 && ((i - 1) % 3 != 0));
  const int wf = (i > 0) ? word_idx[b * T_ + (i - 1)] : 0;
  for (int rep = 0; rep < 2; ++rep) {
    int c = threadIdx.x + rep * 256;
    xr[c] = (i == 0) ? f2b(fc_emb[b * E_ + c])
                     : f2b(ldf(embed_tab, (size_t)wa * E_ + c, F));
    xr[512 + c] = use_f ? f2b(ldf(embed_tab, (size_t)wf * E_ + c, F)) : (u16)0;
  }
}

__global__ __launch_bounds__(256) void pack_bias(
    const void* bH, const void* bI, const void* bf1, const void* bf2,
    const void* bha, const void* bhf, const void* batt, const void* bfc,
    const void* blogit, const void* Walpha,
    float* biasStep, float* bhahf, float* batt_f, float* bfc_f, float* blogit_f,
    float* walpha_f, const int* __restrict__ flagp)
{
  const int F = *flagp;
  int t = blockIdx.x * 256 + threadIdx.x;
  if (t < 1024) biasStep[t] = ldf(bH, t, F);
  else if (t < 1536) biasStep[t] = ldf(bI, t - 1024, F);
  else if (t < 2048) biasStep[t] = ldf(bf1, t - 1536, F);
  else if (t < 2560) biasStep[t] = ldf(bf2, t - 2048, F);
  if (t < 512) {
    bhahf[t] = ldf(bha, t, F) + ldf(bhf, t, F);
    batt_f[t] = ldf(batt, t, F);
    bfc_f[t] = ldf(bfc, t, F);
    walpha_f[t] = ldf(Walpha, t, F);
  }
  if (t < V_) blogit_f[t] = ldf(blogit, t, F);
}

// uniform-weight mean over a (196) of att_proj -> outc[b, seg*64 + lane]
__global__ __launch_bounds__(256) void att_apply_kernel(
    const float* __restrict__ alog, const u16* __restrict__ att_proj,
    float* __restrict__ outc)
{
  int b = blockIdx.x, seg = blockIdx.y, tid = threadIdx.x;
  __shared__ float sw[ATT_];
  __shared__ float rb[256];
  if (alog) {
    float l = (tid < ATT_) ? alog[b * ATT_ + tid] : -3.0e38f;
    rb[tid] = l; __syncthreads();
    for (int s = 128; s; s >>= 1) { if (tid < s) rb[tid] = fmaxf(rb[tid], rb[tid + s]); __syncthreads(); }
    float mx = rb[0]; __syncthreads();
    float e = (tid < ATT_) ? __expf(l - mx) : 0.f;
    rb[tid] = e; __syncthreads();
    for (int s = 128; s; s >>= 1) { if (tid < s) rb[tid] += rb[tid + s]; __syncthreads(); }
    float sum = rb[0]; __syncthreads();
    if (tid < ATT_) sw[tid] = e / sum;
  } else {
    if (tid < ATT_) sw[tid] = 1.f / (float)ATT_;
  }
  __syncthreads();
  int lane = tid & 63, g = tid >> 6;
  int col = seg * 64 + lane;
  float acc = 0.f;
  for (int a = g; a < ATT_; a += 4)
    acc += sw[a] * b2f(att_proj[(size_t)(b * ATT_ + a) * H_ + col]);
  rb[tid] = acc; __syncthreads();
  if (g == 0) outc[b * H_ + col] = rb[lane] + rb[64 + lane] + rb[128 + lane] + rb[192 + lane];
}

// in-place log_softmax over V=10000 per row of d_out (f32)
__global__ __launch_bounds__(256) void logsoftmax_kernel(float* __restrict__ out)
{
  __shared__ float vals[V_];
  __shared__ float rb[256];
  int row = blockIdx.x, tid = threadIdx.x;
  float* p = out + (size_t)row * V_;
  float mx = -3.0e38f;
  for (int c = tid * 4; c < V_; c += 1024) {
    float4 q = *(const float4*)(p + c);
    vals[c] = q.x; vals[c + 1] = q.y; vals[c + 2] = q.z; vals[c + 3] = q.w;
    mx = fmaxf(mx, fmaxf(fmaxf(q.x, q.y), fmaxf(q.z, q.w)));
  }
  rb[tid] = mx; __syncthreads();
  for (int s = 128; s; s >>= 1) { if (tid < s) rb[tid] = fmaxf(rb[tid], rb[tid + s]); __syncthreads(); }
  mx = rb[0]; __syncthreads();
  float sum = 0.f;
  for (int c = tid; c < V_; c += 256) sum += __expf(vals[c] - mx);
  rb[tid] = sum; __syncthreads();
  for (int s = 128; s; s >>= 1) { if (tid < s) rb[tid] += rb[tid + s]; __syncthreads(); }
  float lse = mx + __logf(rb[0]);
  for (int c = tid * 4; c < V_; c += 1024) {
    float4 q;
    q.x = vals[c] - lse; q.y = vals[c + 1] - lse;
    q.z = vals[c + 2] - lse; q.w = vals[c + 3] - lse;
    *(float4*)(p + c) = q;
  }
}

extern "C" void kernel_launch(void* const* d_in, const int* in_sizes, int n_in,
                              void* d_out, int out_size, void* d_ws, size_t ws_size,
                              hipStream_t stream)
{
  const int* word_idx   = (const int*)d_in[0];
  const int* father_idx = (const int*)d_in[1];
  const void* fc_feats  = d_in[2];
  const void* att_feats = d_in[3];
  const void* W_fc      = d_in[4];
  const void* b_fc      = d_in[5];
  const void* W_att     = d_in[6];
  const void* b_att     = d_in[7];
  const void* embed_tab = d_in[8];
  const void* weight_f1 = d_in[9];
  const void* bias_f1   = d_in[10];
  const void* weight_f2 = d_in[11];
  const void* bias_f2   = d_in[12];
  const void* weight_H  = d_in[13];
  const void* bias_H    = d_in[14];
  const void* weight_I  = d_in[15];
  const void* bias_I    = d_in[16];
  const void* W_ha      = d_in[17];
  const void* b_ha      = d_in[18];
  const void* W_hf      = d_in[19];
  const void* b_hf      = d_in[20];
  const void* W_alpha   = d_in[21];
  const void* b_alpha   = d_in[22];   // unused: softmax is shift-invariant
  const void* W_logit   = d_in[23];
  const void* b_logit   = d_in[24];
  (void)b_alpha;

  // ---- d_out (122.88 MB) hosts all dead-before-logits scratch -------------
  char* dob = (char*)d_out;
  size_t doff = 0;
  auto oalloc = [&](size_t bytes) -> char* {
    char* p = dob + doff;
    doff += (bytes + 255) & ~(size_t)255;
    return p;
  };
  u16*  p_att    = (u16*)oalloc((size_t)B_ * ATT_ * E_ * 2);    // 12.85 MB
  u16*  att_proj = (u16*)oalloc((size_t)B_ * ATT_ * H_ * 2);    // 12.85 MB
  u16*  att_bf16 = (u16*)oalloc((size_t)B_ * ATT_ * AF_ * 2);   // 51.38 MB
  float* Gx       = (float*)att_bf16;   // 31.46 MB alias: att_bf16 dead after att GEMMs
  u16*  WstepX   = (u16*)oalloc((size_t)2560 * 1024 * 2);       //  5.24 MB
  u16*  WstepH   = (u16*)oalloc((size_t)2560 * 1024 * 2);       //  5.24 MB
  u16*  Whahf    = (u16*)oalloc((size_t)512 * 1024 * 2);        //  1.05 MB
  u16*  XAll     = (u16*)oalloc((size_t)B_ * T_ * 1024 * 2);    //  6.29 MB
  float* fc_emb   = (float*)oalloc((size_t)B_ * E_ * 4);
  float* att_meanp= (float*)oalloc((size_t)B_ * H_ * 4);
  float* biasStep = (float*)oalloc(2560 * 4);
  float* bhahf    = (float*)oalloc(512 * 4);
  float* batt_f   = (float*)oalloc(512 * 4);
  float* bfc_f    = (float*)oalloc(512 * 4);
  float* walpha_f = (float*)oalloc(512 * 4);
  // total ~95 MB < 122.88 MB ✓

  // ---- only buffers LIVE during the final logits GEMM go in d_ws ----------
  char* ws = (char*)d_ws;
  size_t woff = 0;
  auto walloc = [&](size_t bytes) -> char* {
    char* p = ws + woff;
    woff += (bytes + 255) & ~(size_t)255;
    return p;
  };
  u16*  houts     = (u16*)walloc((size_t)B_ * T_ * H_ * 2);     // 3.15 MB
  float* blogit_f = (float*)walloc((size_t)V_ * 4);
  int*   flag     = (int*)walloc(256);

  detect_f32<<<1, 256, 0, stream>>>((const u16*)att_feats, flag);

  pack_wstep<<<4096, 256, 0, stream>>>(weight_H, weight_I, weight_f1, weight_f2,
                                       WstepX, WstepH, flag);
  pack_whahf<<<2048, 256, 0, stream>>>(W_ha, W_hf, Whahf, flag);
  pack_attf<<<4096, 256, 0, stream>>>(att_feats, att_bf16, flag);
  pack_bias<<<40, 256, 0, stream>>>(bias_H, bias_I, bias_f1, bias_f2, b_ha, b_hf,
                                    b_att, b_fc, b_logit, W_alpha,
                                    biasStep, bhahf, batt_f, bfc_f, blogit_f,
                                    walpha_f, flag);

  // fc_emb = fc_feats @ W_fc^T + b_fc  (f32 out)
  gemm_nt<float><<<dim3(1, 8, 1), 256, 0, stream>>>(
      fc_feats, FC_, 0, MD_DYN, W_fc, FC_, 0, MD_DYN,
      fc_emb, E_, E_, FC_, bfc_f, 0, flag);
  pack_xall<<<B_ * T_, 256, 0, stream>>>(fc_emb, embed_tab, word_idx, father_idx,
                                         XAll, flag);
  // p_att = att_feats @ W_att^T + b_att  (bf16 A, bf16 out)
  gemm_nt<u16><<<dim3(B_ * ATT_ / 64, 8, 1), 256, 0, stream>>>(
      att_bf16, AF_, 0, MD_BF16, W_att, AF_, 0, MD_DYN,
      p_att, E_, E_, AF_, batt_f, 0, flag);
  // att_proj = att_feats @ weight_I[:, 2048:4096]^T  (bf16 A, bf16 out)
  gemm_nt<u16><<<dim3(B_ * ATT_ / 64, 8, 1), 256, 0, stream>>>(
      att_bf16, AF_, 0, MD_BF16, weight_I, 4096, 2048, MD_DYN,
      att_proj, H_, H_, AF_, nullptr, 0, flag);
  // Gx = XAll @ WstepX^T  (x-half of all 48 step-GEMMs, hoisted; bias added
  // in the loop). OVERWRITES att_bf16 (dead after the two att GEMMs).
  gemm_nt<float><<<dim3(B_ * T_ / 64, 2560 / 64, 1), 256, 0, stream>>>(
      XAll, 1024, 0, MD_BF16, WstepX, 1024, 0, MD_BF16,
      Gx, 2560, 2560, 1024, nullptr, 0, flag);
  // att_mean contribution = mean_a att_proj
  att_apply_kernel<<<dim3(B_, 8), 256, 0, stream>>>(nullptr, att_proj, att_meanp);

  // ---- entire T=48 recurrence: 64 independent per-batch blocks ------------
  batch_loop<<<B_, 512, 0, stream>>>(
      WstepH, biasStep, Gx, Whahf, bhahf,
      p_att, walpha_f, att_proj, att_meanp,
      houts, father_idx);

  // logits = houts @ W_logit^T + b_logit -> d_out (f32), then log_softmax.
  gemm_nt<float><<<dim3(B_ * T_ / 64, (V_ + 63) / 64, 1), 256, 0, stream>>>(
      houts, H_, 0, MD_BF16, W_logit, H_, 0, MD_DYN,
      (float*)d_out, V_, V_, H_, blogit_f, 0, flag);
  logsoftmax_kernel<<<B_ * T_, 256, 0, stream>>>((float*)d_out);
}

// Round 7
// 3195.155 us; speedup vs baseline: 3.1771x; 3.1771x over previous
//
#include <hip/hip_runtime.h>
#include <hip/hip_bf16.h>
#include <type_traits>

#define B_   64
#define T_   48
#define H_   512
#define E_   512
#define ATT_ 196
#define AF_  2048
#define FC_  2048
#define V_   10000

typedef unsigned short u16;
typedef unsigned int u32;
using s16x8 = __attribute__((ext_vector_type(8))) short;
using f32x4 = __attribute__((ext_vector_type(4))) float;

// input-storage modes for GEMM/pointwise loaders
#define MD_BF16 0
#define MD_F32  1
#define MD_DYN  2   // resolve from detected flag (d_in float tensors)

__device__ __forceinline__ float b2f(u16 u) {
  union { unsigned int i; float f; } x; x.i = ((unsigned int)u) << 16; return x.f;
}
__device__ __forceinline__ u16 f2b(float f) {
  union { float f; unsigned int i; } x; x.f = f;
  unsigned int r = x.i + 0x7fffu + ((x.i >> 16) & 1u);
  return (u16)(r >> 16);
}
__device__ __forceinline__ float sigmoid_(float x) { return 1.f / (1.f + __expf(-x)); }
__device__ __forceinline__ float tanh_(float x) { return 1.f - 2.f / (__expf(2.f * x) + 1.f); }

__device__ __forceinline__ float ldf(const void* p, size_t i, int f) {
  return f ? ((const float*)p)[i] : b2f(((const u16*)p)[i]);
}
__device__ __forceinline__ s16x8 ld8(const void* p, size_t idx, int f) {
  s16x8 r;
  if (f) {
    const float* q = (const float*)p + idx;
    float4 x = *(const float4*)q;
    float4 y = *(const float4*)(q + 4);
    r[0] = (short)f2b(x.x); r[1] = (short)f2b(x.y);
    r[2] = (short)f2b(x.z); r[3] = (short)f2b(x.w);
    r[4] = (short)f2b(y.x); r[5] = (short)f2b(y.y);
    r[6] = (short)f2b(y.z); r[7] = (short)f2b(y.w);
  } else {
    r = *(const s16x8*)((const u16*)p + idx);
  }
  return r;
}
__device__ __forceinline__ s16x8 zero8() {
  s16x8 r; for (int j = 0; j < 8; j++) r[j] = 0; return r;
}

// storage detector: f32 storage => u16 view of att_feats contains exponent-0xFF
// bit patterns (random mantissa halves) with certainty; bf16 N(0,1) never does.
__global__ void detect_f32(const u16* __restrict__ p, int* __restrict__ flag) {
  __shared__ int sb[256];
  int t = threadIdx.x, bad = 0;
  for (int i = t; i < 65536; i += 256) {
    int e = (p[i] >> 7) & 0xFF;
    bad |= (e == 0xFF) ? 1 : 0;
  }
  sb[t] = bad; __syncthreads();
  for (int s = 128; s; s >>= 1) { if (t < s) sb[t] |= sb[t + s]; __syncthreads(); }
  if (t == 0) *flag = sb[0];
}

// ---------------------------------------------------------------------------
// NT GEMM (one-time GEMMs): C[MxN] = A[MxK] * B[NxK]^T (+bias), bf16 MFMA.
// ---------------------------------------------------------------------------
template <typename CT>
__global__ __launch_bounds__(256) void gemm_nt(
    const void* __restrict__ A, int lda, size_t aoff, int amode,
    const void* __restrict__ B, int ldb, size_t boff, int bmode,
    CT* __restrict__ C, int ldc, int N, int Kc,
    const float* __restrict__ bias, size_t zstride, const int* __restrict__ flagp)
{
  __shared__ __align__(16) u16 As[64 * 40];
  __shared__ __align__(16) u16 Bs[64 * 40];

  const int dynf = *flagp;
  const int aF = (amode == MD_DYN) ? dynf : amode;
  const int bF = (bmode == MD_DYN) ? dynf : bmode;

  const int tid  = threadIdx.x;
  const int m0   = blockIdx.x * 64;
  const int n0   = blockIdx.y * 64;
  const int kz   = blockIdx.z * Kc;
  const int lane = tid & 63;
  const int w    = tid >> 6;
  const int wm   = (w >> 1) * 32;
  const int wn   = (w & 1) * 32;
  const int quad = lane >> 4;
  const int r16  = lane & 15;

  f32x4 acc[2][2];
  for (int a = 0; a < 2; a++) for (int b = 0; b < 2; b++)
    for (int k = 0; k < 4; k++) acc[a][b][k] = 0.f;

  const int sr = tid >> 2;
  const int sc = (tid & 3) * 8;
  const size_t idxA = (size_t)(m0 + sr) * lda + aoff + kz + sc;
  const size_t idxB = (size_t)(n0 + sr) * ldb + boff + kz + sc;
  const bool bok = (n0 + sr) < N;

  const int aoff0 = (wm + r16) * 40 + quad * 8;
  const int aoff1 = (wm + 16 + r16) * 40 + quad * 8;
  const int boff0 = (wn + r16) * 40 + quad * 8;
  const int boff1 = (wn + 16 + r16) * 40 + quad * 8;

  s16x8 av = ld8(A, idxA, aF);
  s16x8 bv = bok ? ld8(B, idxB, bF) : zero8();

  for (int k0 = 0; k0 < Kc; k0 += 32) {
    s16x8 avn = zero8(), bvn = zero8();
    if (k0 + 32 < Kc) {
      avn = ld8(A, idxA + k0 + 32, aF);
      if (bok) bvn = ld8(B, idxB + k0 + 32, bF);
    }
    __syncthreads();
    *(s16x8*)(As + sr * 40 + sc) = av;
    *(s16x8*)(Bs + sr * 40 + sc) = bv;
    __syncthreads();
    s16x8 a0 = *(const s16x8*)(As + aoff0);
    s16x8 a1 = *(const s16x8*)(As + aoff1);
    s16x8 b0 = *(const s16x8*)(Bs + boff0);
    s16x8 b1 = *(const s16x8*)(Bs + boff1);
    acc[0][0] = __builtin_amdgcn_mfma_f32_16x16x32_bf16(a0, b0, acc[0][0], 0, 0, 0);
    acc[0][1] = __builtin_amdgcn_mfma_f32_16x16x32_bf16(a0, b1, acc[0][1], 0, 0, 0);
    acc[1][0] = __builtin_amdgcn_mfma_f32_16x16x32_bf16(a1, b0, acc[1][0], 0, 0, 0);
    acc[1][1] = __builtin_amdgcn_mfma_f32_16x16x32_bf16(a1, b1, acc[1][1], 0, 0, 0);
    av = avn; bv = bvn;
  }

  CT* Cz = C + (size_t)blockIdx.z * zstride;
  const bool addb = (bias != nullptr) && (blockIdx.z == 0);
  for (int tm = 0; tm < 2; tm++)
    for (int tn = 0; tn < 2; tn++) {
      int col = n0 + wn + tn * 16 + r16;
      if (col >= N) continue;
      float bb = addb ? bias[col] : 0.f;
      int rowbase = m0 + wm + tm * 16 + quad * 4;
      for (int rg = 0; rg < 4; rg++) {
        float v = acc[tm][tn][rg] + bb;
        if constexpr (std::is_same<CT, float>::value)
          Cz[(size_t)(rowbase + rg) * ldc + col] = v;
        else
          Cz[(size_t)(rowbase + rg) * ldc + col] = f2b(v);
      }
    }
}

// ---------------------------------------------------------------------------
// PER-STEP kernel 1: both h-GEMMs of a step, weight-shared across batch.
// 88 blocks x 256 threads, 64x64 tiles (proven gemm_nt structure, bf16-only):
//   blk 0..79 : Gbuf[bz] = hcat[64x1024] @ WstepH[2560x1024]^T (+bias on bz0)
//               by = blk%40 (N-tile), bz = blk/40 (split-K, Kc=512)
//   blk 80..87: tatf = hcat @ Whahf[512x1024]^T + bhahf  (Kc=1024, skip at i=0)
// Deterministic blockIdx->XCD mapping keeps each slab L2-resident across steps.
// ---------------------------------------------------------------------------
__global__ __launch_bounds__(256) void step_pre(
    const u16* __restrict__ hcat,
    const u16* __restrict__ WstepH, const float* __restrict__ biasStep,
    float* __restrict__ Gbuf,
    const u16* __restrict__ Whahf, const float* __restrict__ bhahf,
    float* __restrict__ tatf, int do_tat)
{
  __shared__ __align__(16) u16 As[64 * 40];
  __shared__ __align__(16) u16 Bs[64 * 40];

  const int tid = threadIdx.x;
  const int blk = blockIdx.x;
  const int lane = tid & 63;
  const int w    = tid >> 6;
  const int wm   = (w >> 1) * 32;
  const int wn   = (w & 1) * 32;
  const int quad = lane >> 4;
  const int r16  = lane & 15;

  const u16* Bb; float* Cc; const float* bias;
  int kz, Kc, ldc, n0; bool addb;
  if (blk < 80) {
    const int by = blk % 40, bz = blk / 40;
    n0 = by * 64; kz = bz * 512; Kc = 512; ldc = 2560;
    Bb = WstepH; Cc = Gbuf + (size_t)bz * (B_ * 2560);
    bias = biasStep; addb = (bz == 0);
  } else {
    if (!do_tat) return;
    n0 = (blk - 80) * 64; kz = 0; Kc = 1024; ldc = 512;
    Bb = Whahf; Cc = tatf; bias = bhahf; addb = true;
  }

  f32x4 acc[2][2];
  for (int a = 0; a < 2; a++) for (int c = 0; c < 2; c++)
    for (int k = 0; k < 4; k++) acc[a][c][k] = 0.f;

  const int sr = tid >> 2;
  const int sc = (tid & 3) * 8;
  const u16* pa = hcat + (size_t)sr * 1024 + kz + sc;
  const u16* pb = Bb + (size_t)(n0 + sr) * 1024 + kz + sc;

  const int ao0 = (wm + r16) * 40 + quad * 8;
  const int ao1 = (wm + 16 + r16) * 40 + quad * 8;
  const int bo0 = (wn + r16) * 40 + quad * 8;
  const int bo1 = (wn + 16 + r16) * 40 + quad * 8;

  s16x8 av = *(const s16x8*)pa;
  s16x8 bv = *(const s16x8*)pb;

  for (int k0 = 0; k0 < Kc; k0 += 32) {
    s16x8 avn = zero8(), bvn = zero8();
    if (k0 + 32 < Kc) {
      avn = *(const s16x8*)(pa + k0 + 32);
      bvn = *(const s16x8*)(pb + k0 + 32);
    }
    __syncthreads();
    *(s16x8*)(As + sr * 40 + sc) = av;
    *(s16x8*)(Bs + sr * 40 + sc) = bv;
    __syncthreads();
    s16x8 a0 = *(const s16x8*)(As + ao0);
    s16x8 a1 = *(const s16x8*)(As + ao1);
    s16x8 b0 = *(const s16x8*)(Bs + bo0);
    s16x8 b1 = *(const s16x8*)(Bs + bo1);
    acc[0][0] = __builtin_amdgcn_mfma_f32_16x16x32_bf16(a0, b0, acc[0][0], 0, 0, 0);
    acc[0][1] = __builtin_amdgcn_mfma_f32_16x16x32_bf16(a0, b1, acc[0][1], 0, 0, 0);
    acc[1][0] = __builtin_amdgcn_mfma_f32_16x16x32_bf16(a1, b0, acc[1][0], 0, 0, 0);
    acc[1][1] = __builtin_amdgcn_mfma_f32_16x16x32_bf16(a1, b1, acc[1][1], 0, 0, 0);
    av = avn; bv = bvn;
  }

  for (int tm = 0; tm < 2; tm++)
    for (int tn = 0; tn < 2; tn++) {
      int col = n0 + wn + tn * 16 + r16;
      float bb = addb ? bias[col] : 0.f;
      int rowbase = wm + tm * 16 + quad * 4;
      for (int rg = 0; rg < 4; rg++)
        Cc[(size_t)(rowbase + rg) * ldc + col] = acc[tm][tn][rg] + bb;
    }
}

// ---------------------------------------------------------------------------
// PER-STEP kernel 2: attention (logits+softmax+apply, per-batch data only) +
// LSTM finish + next-step hcat build. 64 blocks x 512 threads, thread=element.
// attc never leaves registers. All phases proven in rounds 4-6.
// ---------------------------------------------------------------------------
__global__ __launch_bounds__(512) void att_fin(
    const float* __restrict__ tatf, const u16* __restrict__ p_att,
    const float* __restrict__ walpha_f, const u16* __restrict__ att_proj,
    const float* __restrict__ att_meanp,
    const float* __restrict__ Gbuf, const float* __restrict__ Gx,
    float* __restrict__ c_states, u16* __restrict__ houts,
    u16* __restrict__ hcat, const int* __restrict__ father_idx, int i)
{
  __shared__ float tat_sh[512];
  __shared__ float sl[256];
  __shared__ float red[512];

  const int b = blockIdx.x, tid = threadIdx.x;
  const int lane = tid & 63, w = tid >> 6;
  const int is_first = (i == 0);
  const int use_f = (!is_first) && ((i - 1) % 3 != 0);

  float attv;
  if (is_first) {
    attv = att_meanp[b * H_ + tid];
  } else {
    tat_sh[tid] = tatf[b * H_ + tid];
    __syncthreads();
    // logits: wave w -> a = w, w+8, ...; 1-deep p_att row prefetch
    {
      float t8[8], wa8[8];
#pragma unroll
      for (int j = 0; j < 8; j++) {
        t8[j]  = tat_sh[lane * 8 + j];
        wa8[j] = walpha_f[lane * 8 + j];
      }
      const u16* pb = p_att + (size_t)b * ATT_ * 512 + lane * 8;
      s16x8 pv = *(const s16x8*)(pb + (size_t)w * 512);
      for (int a = w; a < ATT_; a += 8) {
        s16x8 nx = zero8();
        if (a + 8 < ATT_) nx = *(const s16x8*)(pb + (size_t)(a + 8) * 512);
        float acc = 0.f;
#pragma unroll
        for (int j = 0; j < 8; j++)
          acc += wa8[j] * tanh_(t8[j] + b2f((u16)pv[j]));
#pragma unroll
        for (int off = 32; off; off >>= 1) acc += __shfl_down(acc, off);
        if (lane == 0) sl[a] = acc;
        pv = nx;
      }
    }
    __syncthreads();
    // softmax over 196 logits
    float l = (tid < ATT_) ? sl[tid] : -3.0e38f;
    red[tid] = l; __syncthreads();
    for (int s = 256; s; s >>= 1) { if (tid < s) red[tid] = fmaxf(red[tid], red[tid + s]); __syncthreads(); }
    float mx = red[0]; __syncthreads();
    float e = (tid < ATT_) ? __expf(l - mx) : 0.f;
    red[tid] = e; __syncthreads();
    for (int s = 256; s; s >>= 1) { if (tid < s) red[tid] += red[tid + s]; __syncthreads(); }
    float inv = 1.f / red[0];
    __syncthreads();
    if (tid < ATT_) sl[tid] = e * inv;
    __syncthreads();
    // apply: attv = sum_a w[a] * att_proj[b,a,tid]
    {
      const u16* ap = att_proj + (size_t)b * ATT_ * 512 + tid;
      float ac0 = 0.f, ac1 = 0.f, ac2 = 0.f, ac3 = 0.f;
      for (int a = 0; a < ATT_; a += 4) {
        ac0 += sl[a]     * b2f(ap[(size_t)a * 512]);
        ac1 += sl[a + 1] * b2f(ap[(size_t)(a + 1) * 512]);
        ac2 += sl[a + 2] * b2f(ap[(size_t)(a + 2) * 512]);
        ac3 += sl[a + 3] * b2f(ap[(size_t)(a + 3) * 512]);
      }
      attv = (ac0 + ac1) + (ac2 + ac3);
    }
  }

  // ---- LSTM finish (thread tid owns element tid of batch b) ----
  const size_t zs = (size_t)B_ * 2560;
  const float* Gb = Gbuf + (size_t)b * 2560 + tid;   // bias already in split 0
  const float* gx = Gx + ((size_t)i * B_ + b) * 2560 + tid;
  float g0 = Gb[0]    + Gb[zs];
  float g1 = Gb[512]  + Gb[zs + 512];
  float g2 = Gb[1024] + Gb[zs + 1024];
  float g3 = Gb[1536] + Gb[zs + 1536];
  float g4 = Gb[2048] + Gb[zs + 2048];
  float ing  = sigmoid_(g0 + gx[0]);
  float outg = sigmoid_(g1 + gx[512]);
  float cg   = tanh_(g2 + gx[1024] + attv);
  float f1   = sigmoid_(g3 + gx[1536]);
  float f2   = sigmoid_(g4 + gx[2048]);
  const int father = father_idx[b * T_ + i];
  // father==i (or future) reads the memset zeros, matching reference scan state
  float c1 = is_first ? 0.f : c_states[((size_t)b * T_ + father) * H_ + tid];
  float c2 = use_f ? c_states[((size_t)b * T_ + (i - 1)) * H_ + tid] : 0.f;
  float nc = f1 * c1 + f2 * c2 + ing * cg;
  float nh = outg * tanh_(nc);
  size_t o = ((size_t)b * T_ + i) * H_ + tid;
  c_states[o] = nc;
  u16 hb = f2b(nh);
  houts[o] = hb;
  if (i + 1 < T_) {
    const int fn = father_idx[b * T_ + (i + 1)];
    const int use_fn = (i % 3 != 0);
    // h_a: fn==i -> just-computed nh; fn>i -> memset zeros; fn<i -> prior steps
    u16 ha = (fn == i) ? hb : houts[((size_t)b * T_ + fn) * H_ + tid];
    hcat[(size_t)b * 1024 + tid] = ha;
    hcat[(size_t)b * 1024 + 512 + tid] = use_fn ? hb : (u16)0;
  }
}

// --- weight/bias packing (reads d_in floats via flag) ------------------------
// Wstep row space (2560 gates rows over cat=[x_a|x_f|h_a|h_f]) split by K:
// WstepX = cols 0..1023 (x part), WstepH = cols 1024..2047 (h part).
__global__ __launch_bounds__(256) void pack_wstep(
    const void* __restrict__ wH, const void* __restrict__ wI,
    const void* __restrict__ wf1, const void* __restrict__ wf2,
    u16* __restrict__ WstepX, u16* __restrict__ WstepH,
    const int* __restrict__ flagp)
{
  const int F = *flagp;
  for (int idx = blockIdx.x * 256 + threadIdx.x; idx < 2560 * 2048; idx += gridDim.x * 256) {
    int row = idx >> 11, col = idx & 2047;
    float v = 0.f;
    if (row < 1024) v = ldf(wH, (size_t)row * 2048 + col, F);
    else if (row < 1536) v = ldf(wI, (size_t)(row - 1024) * 4096 + col, F);
    else if (row < 2048) {
      int r = row - 1536;
      if (col < 512) v = ldf(wf1, (size_t)r * 1024 + col, F);
      else if (col >= 1024 && col < 1536) v = ldf(wf1, (size_t)r * 1024 + 512 + (col - 1024), F);
    } else {
      int r = row - 2048;
      if (col >= 512 && col < 1024) v = ldf(wf2, (size_t)r * 1024 + (col - 512), F);
      else if (col >= 1536) v = ldf(wf2, (size_t)r * 1024 + 512 + (col - 1536), F);
    }
    if (col < 1024) WstepX[(size_t)row * 1024 + col] = f2b(v);
    else           WstepH[(size_t)row * 1024 + (col - 1024)] = f2b(v);
  }
}

__global__ __launch_bounds__(256) void pack_whahf(
    const void* __restrict__ W_ha, const void* __restrict__ W_hf,
    u16* __restrict__ Whahf, const int* __restrict__ flagp)
{
  const int F = *flagp;
  for (int idx = blockIdx.x * 256 + threadIdx.x; idx < 512 * 1024; idx += gridDim.x * 256) {
    int e = idx >> 10, k = idx & 1023;
    float v = (k < 512) ? ldf(W_ha, (size_t)e * 512 + k, F)
                        : ldf(W_hf, (size_t)e * 512 + (k - 512), F);
    Whahf[idx] = f2b(v);
  }
}

// att_feats -> bf16 copy (zero numerical change: GEMMs already cast to bf16)
__global__ __launch_bounds__(256) void pack_attf(
    const void* __restrict__ src, u16* __restrict__ dst, const int* __restrict__ flagp)
{
  const int F = *flagp;
  const size_t n8 = (size_t)B_ * ATT_ * AF_ / 8;
  for (size_t idx = (size_t)blockIdx.x * 256 + threadIdx.x; idx < n8;
       idx += (size_t)gridDim.x * 256) {
    s16x8 v = ld8(src, idx * 8, F);
    *(s16x8*)(dst + idx * 8) = v;
  }
}

// XAll[i*64+b][0..1023] = [x_a | x_f] for step i, batch b (bf16)
__global__ __launch_bounds__(256) void pack_xall(
    const float* __restrict__ fc_emb, const void* __restrict__ embed_tab,
    const int* __restrict__ word_idx, const int* __restrict__ father_idx,
    u16* __restrict__ XAll, const int* __restrict__ flagp)
{
  const int F = *flagp;
  const int ib = blockIdx.x;          // 0..3071
  const int i = ib >> 6, b = ib & 63;
  u16* xr = XAll + (size_t)ib * 1024;
  const int fa = father_idx[b * T_ + i];
  const int wa = word_idx[b * T_ + fa];
  const int use_f = (i > 0 && ((i - 1) % 3 != 0));
  const int wf = (i > 0) ? word_idx[b * T_ + (i - 1)] : 0;
  for (int rep = 0; rep < 2; ++rep) {
    int c = threadIdx.x + rep * 256;
    xr[c] = (i == 0) ? f2b(fc_emb[b * E_ + c])
                     : f2b(ldf(embed_tab, (size_t)wa * E_ + c, F));
    xr[512 + c] = use_f ? f2b(ldf(embed_tab, (size_t)wf * E_ + c, F)) : (u16)0;
  }
}

__global__ __launch_bounds__(256) void pack_bias(
    const void* bH, const void* bI, const void* bf1, const void* bf2,
    const void* bha, const void* bhf, const void* batt, const void* bfc,
    const void* blogit, const void* Walpha,
    float* biasStep, float* bhahf, float* batt_f, float* bfc_f, float* blogit_f,
    float* walpha_f, const int* __restrict__ flagp)
{
  const int F = *flagp;
  int t = blockIdx.x * 256 + threadIdx.x;
  if (t < 1024) biasStep[t] = ldf(bH, t, F);
  else if (t < 1536) biasStep[t] = ldf(bI, t - 1024, F);
  else if (t < 2048) biasStep[t] = ldf(bf1, t - 1536, F);
  else if (t < 2560) biasStep[t] = ldf(bf2, t - 2048, F);
  if (t < 512) {
    bhahf[t] = ldf(bha, t, F) + ldf(bhf, t, F);
    batt_f[t] = ldf(batt, t, F);
    bfc_f[t] = ldf(bfc, t, F);
    walpha_f[t] = ldf(Walpha, t, F);
  }
  if (t < V_) blogit_f[t] = ldf(blogit, t, F);
}

// uniform-weight mean over a (196) of att_proj -> outc[b, seg*64 + lane]
__global__ __launch_bounds__(256) void att_apply_kernel(
    const float* __restrict__ alog, const u16* __restrict__ att_proj,
    float* __restrict__ outc)
{
  int b = blockIdx.x, seg = blockIdx.y, tid = threadIdx.x;
  __shared__ float sw[ATT_];
  __shared__ float rb[256];
  if (alog) {
    float l = (tid < ATT_) ? alog[b * ATT_ + tid] : -3.0e38f;
    rb[tid] = l; __syncthreads();
    for (int s = 128; s; s >>= 1) { if (tid < s) rb[tid] = fmaxf(rb[tid], rb[tid + s]); __syncthreads(); }
    float mx = rb[0]; __syncthreads();
    float e = (tid < ATT_) ? __expf(l - mx) : 0.f;
    rb[tid] = e; __syncthreads();
    for (int s = 128; s; s >>= 1) { if (tid < s) rb[tid] += rb[tid + s]; __syncthreads(); }
    float sum = rb[0]; __syncthreads();
    if (tid < ATT_) sw[tid] = e / sum;
  } else {
    if (tid < ATT_) sw[tid] = 1.f / (float)ATT_;
  }
  __syncthreads();
  int lane = tid & 63, g = tid >> 6;
  int col = seg * 64 + lane;
  float acc = 0.f;
  for (int a = g; a < ATT_; a += 4)
    acc += sw[a] * b2f(att_proj[(size_t)(b * ATT_ + a) * H_ + col]);
  rb[tid] = acc; __syncthreads();
  if (g == 0) outc[b * H_ + col] = rb[lane] + rb[64 + lane] + rb[128 + lane] + rb[192 + lane];
}

// in-place log_softmax over V=10000 per row of d_out (f32)
__global__ __launch_bounds__(256) void logsoftmax_kernel(float* __restrict__ out)
{
  __shared__ float vals[V_];
  __shared__ float rb[256];
  int row = blockIdx.x, tid = threadIdx.x;
  float* p = out + (size_t)row * V_;
  float mx = -3.0e38f;
  for (int c = tid * 4; c < V_; c += 1024) {
    float4 q = *(const float4*)(p + c);
    vals[c] = q.x; vals[c + 1] = q.y; vals[c + 2] = q.z; vals[c + 3] = q.w;
    mx = fmaxf(mx, fmaxf(fmaxf(q.x, q.y), fmaxf(q.z, q.w)));
  }
  rb[tid] = mx; __syncthreads();
  for (int s = 128; s; s >>= 1) { if (tid < s) rb[tid] = fmaxf(rb[tid], rb[tid + s]); __syncthreads(); }
  mx = rb[0]; __syncthreads();
  float sum = 0.f;
  for (int c = tid; c < V_; c += 256) sum += __expf(vals[c] - mx);
  rb[tid] = sum; __syncthreads();
  for (int s = 128; s; s >>= 1) { if (tid < s) rb[tid] += rb[tid + s]; __syncthreads(); }
  float lse = mx + __logf(rb[0]);
  for (int c = tid * 4; c < V_; c += 1024) {
    float4 q;
    q.x = vals[c] - lse; q.y = vals[c + 1] - lse;
    q.z = vals[c + 2] - lse; q.w = vals[c + 3] - lse;
    *(float4*)(p + c) = q;
  }
}

extern "C" void kernel_launch(void* const* d_in, const int* in_sizes, int n_in,
                              void* d_out, int out_size, void* d_ws, size_t ws_size,
                              hipStream_t stream)
{
  const int* word_idx   = (const int*)d_in[0];
  const int* father_idx = (const int*)d_in[1];
  const void* fc_feats  = d_in[2];
  const void* att_feats = d_in[3];
  const void* W_fc      = d_in[4];
  const void* b_fc      = d_in[5];
  const void* W_att     = d_in[6];
  const void* b_att     = d_in[7];
  const void* embed_tab = d_in[8];
  const void* weight_f1 = d_in[9];
  const void* bias_f1   = d_in[10];
  const void* weight_f2 = d_in[11];
  const void* bias_f2   = d_in[12];
  const void* weight_H  = d_in[13];
  const void* bias_H    = d_in[14];
  const void* weight_I  = d_in[15];
  const void* bias_I    = d_in[16];
  const void* W_ha      = d_in[17];
  const void* b_ha      = d_in[18];
  const void* W_hf      = d_in[19];
  const void* b_hf      = d_in[20];
  const void* W_alpha   = d_in[21];
  const void* b_alpha   = d_in[22];   // unused: softmax is shift-invariant
  const void* W_logit   = d_in[23];
  const void* b_logit   = d_in[24];
  (void)b_alpha;

  // ---- d_out (122.88 MB) hosts all dead-before-logits scratch -------------
  char* dob = (char*)d_out;
  size_t doff = 0;
  auto oalloc = [&](size_t bytes) -> char* {
    char* p = dob + doff;
    doff += (bytes + 255) & ~(size_t)255;
    return p;
  };
  u16*  p_att    = (u16*)oalloc((size_t)B_ * ATT_ * E_ * 2);    // 12.85 MB
  u16*  att_proj = (u16*)oalloc((size_t)B_ * ATT_ * H_ * 2);    // 12.85 MB
  u16*  att_bf16 = (u16*)oalloc((size_t)B_ * ATT_ * AF_ * 2);   // 51.38 MB
  float* Gx       = (float*)att_bf16;   // 31.46 MB alias: att_bf16 dead after att GEMMs
  u16*  WstepX   = (u16*)oalloc((size_t)2560 * 1024 * 2);       //  5.24 MB
  u16*  WstepH   = (u16*)oalloc((size_t)2560 * 1024 * 2);       //  5.24 MB
  u16*  Whahf    = (u16*)oalloc((size_t)512 * 1024 * 2);        //  1.05 MB
  u16*  XAll     = (u16*)oalloc((size_t)B_ * T_ * 1024 * 2);    //  6.29 MB
  float* c_states = (float*)oalloc((size_t)B_ * T_ * H_ * 4);   //  6.29 MB
  float* Gbuf     = (float*)oalloc((size_t)2 * B_ * 2560 * 4);  //  1.31 MB
  u16*  hcat     = (u16*)oalloc((size_t)B_ * 1024 * 2);         //  0.13 MB
  float* tatf     = (float*)oalloc((size_t)B_ * H_ * 4);
  float* fc_emb   = (float*)oalloc((size_t)B_ * E_ * 4);
  float* att_meanp= (float*)oalloc((size_t)B_ * H_ * 4);
  float* biasStep = (float*)oalloc(2560 * 4);
  float* bhahf    = (float*)oalloc(512 * 4);
  float* batt_f   = (float*)oalloc(512 * 4);
  float* bfc_f    = (float*)oalloc(512 * 4);
  float* walpha_f = (float*)oalloc(512 * 4);
  // total ~96 MB < 122.88 MB ✓

  // ---- only buffers LIVE during the final logits GEMM go in d_ws ----------
  char* ws = (char*)d_ws;
  size_t woff = 0;
  auto walloc = [&](size_t bytes) -> char* {
    char* p = ws + woff;
    woff += (bytes + 255) & ~(size_t)255;
    return p;
  };
  u16*  houts     = (u16*)walloc((size_t)B_ * T_ * H_ * 2);     // 3.15 MB
  float* blogit_f = (float*)walloc((size_t)V_ * 4);
  int*   flag     = (int*)walloc(256);

  hipMemsetAsync(c_states, 0, (size_t)B_ * T_ * H_ * 4, stream);
  hipMemsetAsync(houts, 0, (size_t)B_ * T_ * H_ * 2, stream);
  hipMemsetAsync(hcat, 0, (size_t)B_ * 1024 * 2, stream);

  detect_f32<<<1, 256, 0, stream>>>((const u16*)att_feats, flag);

  pack_wstep<<<4096, 256, 0, stream>>>(weight_H, weight_I, weight_f1, weight_f2,
                                       WstepX, WstepH, flag);
  pack_whahf<<<2048, 256, 0, stream>>>(W_ha, W_hf, Whahf, flag);
  pack_attf<<<4096, 256, 0, stream>>>(att_feats, att_bf16, flag);
  pack_bias<<<40, 256, 0, stream>>>(bias_H, bias_I, bias_f1, bias_f2, b_ha, b_hf,
                                    b_att, b_fc, b_logit, W_alpha,
                                    biasStep, bhahf, batt_f, bfc_f, blogit_f,
                                    walpha_f, flag);

  // fc_emb = fc_feats @ W_fc^T + b_fc  (f32 out)
  gemm_nt<float><<<dim3(1, 8, 1), 256, 0, stream>>>(
      fc_feats, FC_, 0, MD_DYN, W_fc, FC_, 0, MD_DYN,
      fc_emb, E_, E_, FC_, bfc_f, 0, flag);
  pack_xall<<<B_ * T_, 256, 0, stream>>>(fc_emb, embed_tab, word_idx, father_idx,
                                         XAll, flag);
  // p_att = att_feats @ W_att^T + b_att  (bf16 A, bf16 out)
  gemm_nt<u16><<<dim3(B_ * ATT_ / 64, 8, 1), 256, 0, stream>>>(
      att_bf16, AF_, 0, MD_BF16, W_att, AF_, 0, MD_DYN,
      p_att, E_, E_, AF_, batt_f, 0, flag);
  // att_proj = att_feats @ weight_I[:, 2048:4096]^T  (bf16 A, bf16 out)
  gemm_nt<u16><<<dim3(B_ * ATT_ / 64, 8, 1), 256, 0, stream>>>(
      att_bf16, AF_, 0, MD_BF16, weight_I, 4096, 2048, MD_DYN,
      att_proj, H_, H_, AF_, nullptr, 0, flag);
  // Gx = XAll @ WstepX^T  (x-half of all 48 step-GEMMs, hoisted; bias added
  // inside the loop GEMM). OVERWRITES att_bf16 (dead after the att GEMMs).
  gemm_nt<float><<<dim3(B_ * T_ / 64, 2560 / 64, 1), 256, 0, stream>>>(
      XAll, 1024, 0, MD_BF16, WstepX, 1024, 0, MD_BF16,
      Gx, 2560, 2560, 1024, nullptr, 0, flag);
  // att_mean contribution = mean_a att_proj
  att_apply_kernel<<<dim3(B_, 8), 256, 0, stream>>>(nullptr, att_proj, att_meanp);

  // ---- T=48 loop: 2 dependent kernels per step ----------------------------
  for (int i = 0; i < T_; ++i) {
    step_pre<<<88, 256, 0, stream>>>(hcat, WstepH, biasStep, Gbuf,
                                     Whahf, bhahf, tatf, i > 0 ? 1 : 0);
    att_fin<<<B_, 512, 0, stream>>>(tatf, p_att, walpha_f, att_proj, att_meanp,
                                    Gbuf, Gx, c_states, houts, hcat,
                                    father_idx, i);
  }

  // logits = houts @ W_logit^T + b_logit -> d_out (f32), then log_softmax.
  gemm_nt<float><<<dim3(B_ * T_ / 64, (V_ + 63) / 64, 1), 256, 0, stream>>>(
      houts, H_, 0, MD_BF16, W_logit, H_, 0, MD_DYN,
      (float*)d_out, V_, V_, H_, blogit_f, 0, flag);
  logsoftmax_kernel<<<B_ * T_, 256, 0, stream>>>((float*)d_out);
}

// Round 8
// 2989.310 us; speedup vs baseline: 3.3959x; 1.0689x over previous
//
#include <hip/hip_runtime.h>
#include <hip/hip_bf16.h>
#include <type_traits>

#define B_   64
#define T_   48
#define H_   512
#define E_   512
#define ATT_ 196
#define AF_  2048
#define FC_  2048
#define V_   10000
#define GB_N 3072   // gates (2560) + tat (512) output columns

typedef unsigned short u16;
typedef unsigned int u32;
typedef unsigned long long u64;
using s16x8 = __attribute__((ext_vector_type(8))) short;
using f32x4 = __attribute__((ext_vector_type(4))) float;

// input-storage modes for GEMM/pointwise loaders
#define MD_BF16 0
#define MD_F32  1
#define MD_DYN  2   // resolve from detected flag (d_in float tensors)

__device__ __forceinline__ float b2f(u16 u) {
  union { unsigned int i; float f; } x; x.i = ((unsigned int)u) << 16; return x.f;
}
__device__ __forceinline__ u16 f2b(float f) {
  union { float f; unsigned int i; } x; x.f = f;
  unsigned int r = x.i + 0x7fffu + ((x.i >> 16) & 1u);
  return (u16)(r >> 16);
}
__device__ __forceinline__ float sigmoid_(float x) { return 1.f / (1.f + __expf(-x)); }
__device__ __forceinline__ float tanh_(float x) { return 1.f - 2.f / (__expf(2.f * x) + 1.f); }

__device__ __forceinline__ float ldf(const void* p, size_t i, int f) {
  return f ? ((const float*)p)[i] : b2f(((const u16*)p)[i]);
}
__device__ __forceinline__ s16x8 ld8(const void* p, size_t idx, int f) {
  s16x8 r;
  if (f) {
    const float* q = (const float*)p + idx;
    float4 x = *(const float4*)q;
    float4 y = *(const float4*)(q + 4);
    r[0] = (short)f2b(x.x); r[1] = (short)f2b(x.y);
    r[2] = (short)f2b(x.z); r[3] = (short)f2b(x.w);
    r[4] = (short)f2b(y.x); r[5] = (short)f2b(y.y);
    r[6] = (short)f2b(y.z); r[7] = (short)f2b(y.w);
  } else {
    r = *(const s16x8*)((const u16*)p + idx);
  }
  return r;
}
__device__ __forceinline__ s16x8 zero8() {
  s16x8 r; for (int j = 0; j < 8; j++) r[j] = 0; return r;
}

// ---- agent-scope relaxed atomics (proven rounds 4-6): device-coherent via
// coherence point, bypassing the non-coherent per-XCD L2. Used ONLY for the
// 128 KB hcat crossing the intra-kernel producer->consumer boundary.
__device__ __forceinline__ u64 aload_u64(const u64* p) {
  return __hip_atomic_load(p, __ATOMIC_RELAXED, __HIP_MEMORY_SCOPE_AGENT);
}
__device__ __forceinline__ void astore_u32(u32* p, u32 v) {
  __hip_atomic_store(p, v, __ATOMIC_RELAXED, __HIP_MEMORY_SCOPE_AGENT);
}
__device__ __forceinline__ s16x8 ld8_coh(const u16* p) {
  union { u64 u[2]; s16x8 v; } x;
  x.u[0] = aload_u64((const u64*)p);
  x.u[1] = aload_u64((const u64*)p + 1);
  return x.v;
}

// storage detector: f32 storage => u16 view of att_feats contains exponent-0xFF
// bit patterns (random mantissa halves) with certainty; bf16 N(0,1) never does.
__global__ void detect_f32(const u16* __restrict__ p, int* __restrict__ flag) {
  __shared__ int sb[256];
  int t = threadIdx.x, bad = 0;
  for (int i = t; i < 65536; i += 256) {
    int e = (p[i] >> 7) & 0xFF;
    bad |= (e == 0xFF) ? 1 : 0;
  }
  sb[t] = bad; __syncthreads();
  for (int s = 128; s; s >>= 1) { if (t < s) sb[t] |= sb[t + s]; __syncthreads(); }
  if (t == 0) *flag = sb[0];
}

// ---------------------------------------------------------------------------
// NT GEMM (one-time GEMMs): C[MxN] = A[MxK] * B[NxK]^T (+bias), bf16 MFMA.
// ---------------------------------------------------------------------------
template <typename CT>
__global__ __launch_bounds__(256) void gemm_nt(
    const void* __restrict__ A, int lda, size_t aoff, int amode,
    const void* __restrict__ B, int ldb, size_t boff, int bmode,
    CT* __restrict__ C, int ldc, int N, int Kc,
    const float* __restrict__ bias, size_t zstride, const int* __restrict__ flagp)
{
  __shared__ __align__(16) u16 As[64 * 40];
  __shared__ __align__(16) u16 Bs[64 * 40];

  const int dynf = *flagp;
  const int aF = (amode == MD_DYN) ? dynf : amode;
  const int bF = (bmode == MD_DYN) ? dynf : bmode;

  const int tid  = threadIdx.x;
  const int m0   = blockIdx.x * 64;
  const int n0   = blockIdx.y * 64;
  const int kz   = blockIdx.z * Kc;
  const int lane = tid & 63;
  const int w    = tid >> 6;
  const int wm   = (w >> 1) * 32;
  const int wn   = (w & 1) * 32;
  const int quad = lane >> 4;
  const int r16  = lane & 15;

  f32x4 acc[2][2];
  for (int a = 0; a < 2; a++) for (int b = 0; b < 2; b++)
    for (int k = 0; k < 4; k++) acc[a][b][k] = 0.f;

  const int sr = tid >> 2;
  const int sc = (tid & 3) * 8;
  const size_t idxA = (size_t)(m0 + sr) * lda + aoff + kz + sc;
  const size_t idxB = (size_t)(n0 + sr) * ldb + boff + kz + sc;
  const bool bok = (n0 + sr) < N;

  const int aoff0 = (wm + r16) * 40 + quad * 8;
  const int aoff1 = (wm + 16 + r16) * 40 + quad * 8;
  const int boff0 = (wn + r16) * 40 + quad * 8;
  const int boff1 = (wn + 16 + r16) * 40 + quad * 8;

  s16x8 av = ld8(A, idxA, aF);
  s16x8 bv = bok ? ld8(B, idxB, bF) : zero8();

  for (int k0 = 0; k0 < Kc; k0 += 32) {
    s16x8 avn = zero8(), bvn = zero8();
    if (k0 + 32 < Kc) {
      avn = ld8(A, idxA + k0 + 32, aF);
      if (bok) bvn = ld8(B, idxB + k0 + 32, bF);
    }
    __syncthreads();
    *(s16x8*)(As + sr * 40 + sc) = av;
    *(s16x8*)(Bs + sr * 40 + sc) = bv;
    __syncthreads();
    s16x8 a0 = *(const s16x8*)(As + aoff0);
    s16x8 a1 = *(const s16x8*)(As + aoff1);
    s16x8 b0 = *(const s16x8*)(Bs + boff0);
    s16x8 b1 = *(const s16x8*)(Bs + boff1);
    acc[0][0] = __builtin_amdgcn_mfma_f32_16x16x32_bf16(a0, b0, acc[0][0], 0, 0, 0);
    acc[0][1] = __builtin_amdgcn_mfma_f32_16x16x32_bf16(a0, b1, acc[0][1], 0, 0, 0);
    acc[1][0] = __builtin_amdgcn_mfma_f32_16x16x32_bf16(a1, b0, acc[1][0], 0, 0, 0);
    acc[1][1] = __builtin_amdgcn_mfma_f32_16x16x32_bf16(a1, b1, acc[1][1], 0, 0, 0);
    av = avn; bv = bvn;
  }

  CT* Cz = C + (size_t)blockIdx.z * zstride;
  const bool addb = (bias != nullptr) && (blockIdx.z == 0);
  for (int tm = 0; tm < 2; tm++)
    for (int tn = 0; tn < 2; tn++) {
      int col = n0 + wn + tn * 16 + r16;
      if (col >= N) continue;
      float bb = addb ? bias[col] : 0.f;
      int rowbase = m0 + wm + tm * 16 + quad * 4;
      for (int rg = 0; rg < 4; rg++) {
        float v = acc[tm][tn][rg] + bb;
        if constexpr (std::is_same<CT, float>::value)
          Cz[(size_t)(rowbase + rg) * ldc + col] = v;
        else
          Cz[(size_t)(rowbase + rg) * ldc + col] = f2b(v);
      }
    }
}

// ---------------------------------------------------------------------------
// Logits GEMM with XCD-chunked N-tiling: XCD k (= blockIdx%8) owns N-tiles
// [20k, 20k+20) so its L2 holds a 1.3 MB W_logit slice instead of all 10 MB.
// C = houts[3072x512](bf16) @ W_logit[10000x512]^T + b_logit, f32 out.
// ---------------------------------------------------------------------------
__global__ __launch_bounds__(256) void gemm_logit(
    const u16* __restrict__ A, const void* __restrict__ B,
    float* __restrict__ C, const float* __restrict__ bias,
    const int* __restrict__ flagp)
{
  __shared__ __align__(16) u16 As[64 * 40];
  __shared__ __align__(16) u16 Bs[64 * 40];

  const int bF = *flagp;
  const int bid = blockIdx.x;
  const int xcd = bid & 7, rest = bid >> 3;
  const int yl = rest % 20, xt = rest / 20;
  const int m0 = xt * 64;
  const int n0 = (xcd * 20 + yl) * 64;     // up to 10176; guarded below

  const int tid  = threadIdx.x;
  const int lane = tid & 63;
  const int w    = tid >> 6;
  const int wm   = (w >> 1) * 32;
  const int wn   = (w & 1) * 32;
  const int quad = lane >> 4;
  const int r16  = lane & 15;

  f32x4 acc[2][2];
  for (int a = 0; a < 2; a++) for (int b = 0; b < 2; b++)
    for (int k = 0; k < 4; k++) acc[a][b][k] = 0.f;

  const int sr = tid >> 2;
  const int sc = (tid & 3) * 8;
  const u16* pa = A + (size_t)(m0 + sr) * 512 + sc;
  const size_t idxB = (size_t)(n0 + sr) * 512 + sc;
  const bool bok = (n0 + sr) < V_;

  const int ao0 = (wm + r16) * 40 + quad * 8;
  const int ao1 = (wm + 16 + r16) * 40 + quad * 8;
  const int bo0 = (wn + r16) * 40 + quad * 8;
  const int bo1 = (wn + 16 + r16) * 40 + quad * 8;

  s16x8 av = *(const s16x8*)pa;
  s16x8 bv = bok ? ld8(B, idxB, bF) : zero8();

  for (int k0 = 0; k0 < 512; k0 += 32) {
    s16x8 avn = zero8(), bvn = zero8();
    if (k0 + 32 < 512) {
      avn = *(const s16x8*)(pa + k0 + 32);
      if (bok) bvn = ld8(B, idxB + k0 + 32, bF);
    }
    __syncthreads();
    *(s16x8*)(As + sr * 40 + sc) = av;
    *(s16x8*)(Bs + sr * 40 + sc) = bv;
    __syncthreads();
    s16x8 a0 = *(const s16x8*)(As + ao0);
    s16x8 a1 = *(const s16x8*)(As + ao1);
    s16x8 b0 = *(const s16x8*)(Bs + bo0);
    s16x8 b1 = *(const s16x8*)(Bs + bo1);
    acc[0][0] = __builtin_amdgcn_mfma_f32_16x16x32_bf16(a0, b0, acc[0][0], 0, 0, 0);
    acc[0][1] = __builtin_amdgcn_mfma_f32_16x16x32_bf16(a0, b1, acc[0][1], 0, 0, 0);
    acc[1][0] = __builtin_amdgcn_mfma_f32_16x16x32_bf16(a1, b0, acc[1][0], 0, 0, 0);
    acc[1][1] = __builtin_amdgcn_mfma_f32_16x16x32_bf16(a1, b1, acc[1][1], 0, 0, 0);
    av = avn; bv = bvn;
  }

  for (int tm = 0; tm < 2; tm++)
    for (int tn = 0; tn < 2; tn++) {
      int col = n0 + wn + tn * 16 + r16;
      if (col >= V_) continue;
      float bb = bias[col];
      int rowbase = m0 + wm + tm * 16 + quad * 4;
      for (int rg = 0; rg < 4; rg++)
        C[(size_t)(rowbase + rg) * V_ + col] = acc[tm][tn][rg] + bb;
    }
}

// Gbuf init for step 0: h inputs are zero => gates = bias (z0), 0 (z1)
__global__ __launch_bounds__(512) void ginit(float* __restrict__ G,
                                             const float* __restrict__ biasComb)
{
  const size_t idx = (size_t)blockIdx.x * 512 + threadIdx.x;   // < 64*3072
  const int c = (int)(idx % GB_N);
  G[idx] = biasComb[c];
  G[(size_t)B_ * GB_N + idx] = 0.f;
}

// ---------------------------------------------------------------------------
// MERGED per-step kernel. 112 blocks x 512 threads, all co-resident.
//  blocks 0..63  : attention(i) [round-7 att_fin verbatim] + LSTM finish(i)
//                  + hcat(i+1) build (agent-atomic u32 stores, round-4 proven)
//                  + vmcnt drain + count into monotonic barcnt.
//  blocks 64..111: gates+tat GEMM for step i+1 (round-5 proven 128-wide tile):
//                  warm Wcomb slab into L2 (overlaps attention), spin until
//                  barcnt >= 64*(i+1), A=hcat via up-front agent-atomic reg
//                  preload, B normal (L2), write Gnext[2][64][3072] normally
//                  (consumed next launch; kernel boundary gives visibility).
//  Gbuf cols 0..2559 = gates (5 segs), 2560..3071 = tat. bias in z0.
// ---------------------------------------------------------------------------
__global__ __launch_bounds__(512) void step_full(
    const float* __restrict__ Gprev, float* __restrict__ Gnext,
    const u16* __restrict__ p_att, const float* __restrict__ walpha_f,
    const u16* __restrict__ att_proj, const float* __restrict__ att_meanp,
    const float* __restrict__ Gx,
    float* __restrict__ c_states, u16* __restrict__ houts,
    u16* __restrict__ hcat, const int* __restrict__ father_idx,
    const u16* __restrict__ Wcomb, const float* __restrict__ biasComb,
    int* __restrict__ barcnt, int btarget, int i)
{
  const int blk = blockIdx.x, tid = threadIdx.x;
  const int lane = tid & 63, w = tid >> 6;
  const size_t zs = (size_t)B_ * GB_N;

  if (blk < 64) {
    // ======================= attention + finish =======================
    __shared__ float tat_sh[512];
    __shared__ float sl[256];
    __shared__ float red[512];
    __shared__ u16 nh_sh[512];
    __shared__ u16 ha_sh[512];

    const int b = blk;
    const int is_first = (i == 0);
    const int use_f = (!is_first) && ((i - 1) % 3 != 0);

    // early independent loads (hide latency under attention)
    const float* Gb = Gprev + (size_t)b * GB_N + tid;
    float g0 = Gb[0]    + Gb[zs];
    float g1 = Gb[512]  + Gb[zs + 512];
    float g2 = Gb[1024] + Gb[zs + 1024];
    float g3 = Gb[1536] + Gb[zs + 1536];
    float g4 = Gb[2048] + Gb[zs + 2048];
    const float* gx = Gx + ((size_t)i * B_ + b) * 2560 + tid;
    float gx0 = gx[0], gx1 = gx[512], gx2 = gx[1024];
    float gx3 = gx[1536], gx4 = gx[2048];

    float attv;
    if (is_first) {
      attv = att_meanp[b * H_ + tid];
    } else {
      tat_sh[tid] = Gb[2560] + Gb[zs + 2560];   // bias (bhahf) already in z0
      __syncthreads();
      // logits: wave w -> a = w, w+8, ...; 1-deep p_att row prefetch
      {
        float t8[8], wa8[8];
#pragma unroll
        for (int j = 0; j < 8; j++) {
          t8[j]  = tat_sh[lane * 8 + j];
          wa8[j] = walpha_f[lane * 8 + j];
        }
        const u16* pb = p_att + (size_t)b * ATT_ * 512 + lane * 8;
        s16x8 pv = *(const s16x8*)(pb + (size_t)w * 512);
        for (int a = w; a < ATT_; a += 8) {
          s16x8 nx = zero8();
          if (a + 8 < ATT_) nx = *(const s16x8*)(pb + (size_t)(a + 8) * 512);
          float acc = 0.f;
#pragma unroll
          for (int j = 0; j < 8; j++)
            acc += wa8[j] * tanh_(t8[j] + b2f((u16)pv[j]));
#pragma unroll
          for (int off = 32; off; off >>= 1) acc += __shfl_down(acc, off);
          if (lane == 0) sl[a] = acc;
          pv = nx;
        }
      }
      __syncthreads();
      // softmax over 196 logits
      float l = (tid < ATT_) ? sl[tid] : -3.0e38f;
      red[tid] = l; __syncthreads();
      for (int s = 256; s; s >>= 1) { if (tid < s) red[tid] = fmaxf(red[tid], red[tid + s]); __syncthreads(); }
      float mx = red[0]; __syncthreads();
      float e = (tid < ATT_) ? __expf(l - mx) : 0.f;
      red[tid] = e; __syncthreads();
      for (int s = 256; s; s >>= 1) { if (tid < s) red[tid] += red[tid + s]; __syncthreads(); }
      float inv = 1.f / red[0];
      __syncthreads();
      if (tid < ATT_) sl[tid] = e * inv;
      __syncthreads();
      // apply: attv = sum_a w[a] * att_proj[b,a,tid]
      {
        const u16* ap = att_proj + (size_t)b * ATT_ * 512 + tid;
        float ac0 = 0.f, ac1 = 0.f, ac2 = 0.f, ac3 = 0.f;
        for (int a = 0; a < ATT_; a += 4) {
          ac0 += sl[a]     * b2f(ap[(size_t)a * 512]);
          ac1 += sl[a + 1] * b2f(ap[(size_t)(a + 1) * 512]);
          ac2 += sl[a + 2] * b2f(ap[(size_t)(a + 2) * 512]);
          ac3 += sl[a + 3] * b2f(ap[(size_t)(a + 3) * 512]);
        }
        attv = (ac0 + ac1) + (ac2 + ac3);
      }
    }

    // ---- LSTM finish (thread tid owns element tid of batch b) ----
    float ing  = sigmoid_(g0 + gx0);
    float outg = sigmoid_(g1 + gx1);
    float cg   = tanh_(g2 + gx2 + attv);
    float f1   = sigmoid_(g3 + gx3);
    float f2   = sigmoid_(g4 + gx4);
    const int father = father_idx[b * T_ + i];
    // father==i (or future) reads the memset zeros, matching reference scan
    float c1 = is_first ? 0.f : c_states[((size_t)b * T_ + father) * H_ + tid];
    float c2 = use_f ? c_states[((size_t)b * T_ + (i - 1)) * H_ + tid] : 0.f;
    float nc = f1 * c1 + f2 * c2 + ing * cg;
    float nh = outg * tanh_(nc);
    size_t o = ((size_t)b * T_ + i) * H_ + tid;
    c_states[o] = nc;
    u16 hb = f2b(nh);
    houts[o] = hb;
    if (i + 1 < T_) {
      const int fn = father_idx[b * T_ + (i + 1)];
      const int use_fn = (i % 3 != 0);
      nh_sh[tid] = hb;
      // h_a: fn==i -> just-computed nh; fn>i -> memset zeros; fn<i -> prior
      ha_sh[tid] = (fn == i) ? hb : houts[((size_t)b * T_ + fn) * H_ + tid];
      __syncthreads();
      if (tid < 256) {
        u32 aw = (u32)ha_sh[2 * tid] | ((u32)ha_sh[2 * tid + 1] << 16);
        u32 fw = use_fn ? ((u32)nh_sh[2 * tid] | ((u32)nh_sh[2 * tid + 1] << 16)) : 0u;
        astore_u32((u32*)(hcat + (size_t)b * 1024) + tid, aw);
        astore_u32((u32*)(hcat + (size_t)b * 1024 + 512) + tid, fw);
      }
    }
    // drain hcat stores, then count in (monotonic counter, no reset)
    asm volatile("s_waitcnt vmcnt(0)" ::: "memory");
    __syncthreads();
    if (tid == 0)
      __hip_atomic_fetch_add(barcnt, 1, __ATOMIC_RELAXED, __HIP_MEMORY_SCOPE_AGENT);
    return;
  }

  // ======================= gates+tat GEMM (step i+1) =======================
  if (i + 1 >= T_) return;
  __shared__ __align__(16) u16 As[64 * 40];
  __shared__ __align__(16) u16 Bs[128 * 40];

  const int g  = blk - 64;            // 0..47
  const int ny = g % 24, z = g / 24;  // 24 N-tiles (128 wide) x 2 split-K
  const int n0 = ny * 128, kz = z * 512;
  const int wm = (w & 1) * 32;
  const int wn = (w >> 1) * 32;
  const int quad = lane >> 4;
  const int r16  = lane & 15;

  // warm this block's Wcomb slab into L2 while attention runs
  {
    const u16* wb = Wcomb + (size_t)n0 * 1024 + kz;
    for (int l = tid; l < 1024; l += 512) {   // 128 rows x 8 lines(128B)/row
      const volatile u32* pl =
          (const volatile u32*)(wb + (size_t)(l >> 3) * 1024 + (l & 7) * 64);
      (void)*pl;
    }
  }
  // wait for all 64 attention blocks of this step
  if (tid == 0) {
    while (__hip_atomic_load(barcnt, __ATOMIC_RELAXED, __HIP_MEMORY_SCOPE_AGENT) < btarget)
      __builtin_amdgcn_s_sleep(2);
  }
  __syncthreads();

  // A slab (hcat, device-coherent) -> registers, all loads issued up-front
  const int r  = tid & 255;
  const int sr = r >> 2;            // hcat row 0..63
  const int sc = (r & 3) * 8;
  s16x8 areg[16];
  if (tid < 256) {
    const u16* ap = hcat + (size_t)sr * 1024 + kz + sc;
#pragma unroll
    for (int it = 0; it < 16; ++it) areg[it] = ld8_coh(ap + it * 32);
  }
  const int br = tid >> 2;          // B row 0..127
  const int bc = (tid & 3) * 8;
  const u16* bp = Wcomb + (size_t)(n0 + br) * 1024 + kz + bc;

  f32x4 acc[2][2];
#pragma unroll
  for (int a = 0; a < 2; a++)
#pragma unroll
    for (int c = 0; c < 2; c++)
#pragma unroll
      for (int k = 0; k < 4; k++) acc[a][c][k] = 0.f;

  const int ao0 = (wm + r16) * 40 + quad * 8;
  const int ao1 = (wm + 16 + r16) * 40 + quad * 8;
  const int bo0 = (wn + r16) * 40 + quad * 8;
  const int bo1 = (wn + 16 + r16) * 40 + quad * 8;

  s16x8 bv = *(const s16x8*)bp;
#pragma unroll
  for (int it = 0; it < 16; ++it) {
    s16x8 bn = zero8();
    if (it + 1 < 16) bn = *(const s16x8*)(bp + (it + 1) * 32);
    __syncthreads();
    if (tid < 256) *(s16x8*)(As + sr * 40 + sc) = areg[it];
    *(s16x8*)(Bs + br * 40 + bc) = bv;
    __syncthreads();
    s16x8 a0 = *(const s16x8*)(As + ao0);
    s16x8 a1 = *(const s16x8*)(As + ao1);
    s16x8 b0 = *(const s16x8*)(Bs + bo0);
    s16x8 b1 = *(const s16x8*)(Bs + bo1);
    acc[0][0] = __builtin_amdgcn_mfma_f32_16x16x32_bf16(a0, b0, acc[0][0], 0, 0, 0);
    acc[0][1] = __builtin_amdgcn_mfma_f32_16x16x32_bf16(a0, b1, acc[0][1], 0, 0, 0);
    acc[1][0] = __builtin_amdgcn_mfma_f32_16x16x32_bf16(a1, b0, acc[1][0], 0, 0, 0);
    acc[1][1] = __builtin_amdgcn_mfma_f32_16x16x32_bf16(a1, b1, acc[1][1], 0, 0, 0);
    bv = bn;
  }

  float* Cz = Gnext + (size_t)z * zs;
#pragma unroll
  for (int tm = 0; tm < 2; tm++)
#pragma unroll
    for (int tn = 0; tn < 2; tn++) {
      int col = n0 + wn + tn * 16 + r16;
      float bb = (z == 0) ? biasComb[col] : 0.f;
      int row0 = wm + tm * 16 + quad * 4;
#pragma unroll
      for (int rg = 0; rg < 4; rg++)
        Cz[(size_t)(row0 + rg) * GB_N + col] = acc[tm][tn][rg] + bb;
    }
}

// --- weight/bias packing (reads d_in floats via flag) ------------------------
// Wstep row space (2560 gates rows over cat=[x_a|x_f|h_a|h_f]) split by K:
// WstepX = cols 0..1023 (x part), Wcomb rows 0..2559 = cols 1024..2047 (h),
// Wcomb rows 2560..3071 = Whahf (tat GEMM folded in).
__global__ __launch_bounds__(256) void pack_wstep(
    const void* __restrict__ wH, const void* __restrict__ wI,
    const void* __restrict__ wf1, const void* __restrict__ wf2,
    u16* __restrict__ WstepX, u16* __restrict__ Wcomb,
    const int* __restrict__ flagp)
{
  const int F = *flagp;
  for (int idx = blockIdx.x * 256 + threadIdx.x; idx < 2560 * 2048; idx += gridDim.x * 256) {
    int row = idx >> 11, col = idx & 2047;
    float v = 0.f;
    if (row < 1024) v = ldf(wH, (size_t)row * 2048 + col, F);
    else if (row < 1536) v = ldf(wI, (size_t)(row - 1024) * 4096 + col, F);
    else if (row < 2048) {
      int r = row - 1536;
      if (col < 512) v = ldf(wf1, (size_t)r * 1024 + col, F);
      else if (col >= 1024 && col < 1536) v = ldf(wf1, (size_t)r * 1024 + 512 + (col - 1024), F);
    } else {
      int r = row - 2048;
      if (col >= 512 && col < 1024) v = ldf(wf2, (size_t)r * 1024 + (col - 512), F);
      else if (col >= 1536) v = ldf(wf2, (size_t)r * 1024 + 512 + (col - 1536), F);
    }
    if (col < 1024) WstepX[(size_t)row * 1024 + col] = f2b(v);
    else           Wcomb[(size_t)row * 1024 + (col - 1024)] = f2b(v);
  }
}

__global__ __launch_bounds__(256) void pack_whahf(
    const void* __restrict__ W_ha, const void* __restrict__ W_hf,
    u16* __restrict__ Wcomb, const int* __restrict__ flagp)
{
  const int F = *flagp;
  for (int idx = blockIdx.x * 256 + threadIdx.x; idx < 512 * 1024; idx += gridDim.x * 256) {
    int e = idx >> 10, k = idx & 1023;
    float v = (k < 512) ? ldf(W_ha, (size_t)e * 512 + k, F)
                        : ldf(W_hf, (size_t)e * 512 + (k - 512), F);
    Wcomb[(size_t)2560 * 1024 + idx] = f2b(v);
  }
}

// att_feats -> bf16 copy (zero numerical change: GEMMs already cast to bf16)
__global__ __launch_bounds__(256) void pack_attf(
    const void* __restrict__ src, u16* __restrict__ dst, const int* __restrict__ flagp)
{
  const int F = *flagp;
  const size_t n8 = (size_t)B_ * ATT_ * AF_ / 8;
  for (size_t idx = (size_t)blockIdx.x * 256 + threadIdx.x; idx < n8;
       idx += (size_t)gridDim.x * 256) {
    s16x8 v = ld8(src, idx * 8, F);
    *(s16x8*)(dst + idx * 8) = v;
  }
}

// XAll[i*64+b][0..1023] = [x_a | x_f] for step i, batch b (bf16)
__global__ __launch_bounds__(256) void pack_xall(
    const float* __restrict__ fc_emb, const void* __restrict__ embed_tab,
    const int* __restrict__ word_idx, const int* __restrict__ father_idx,
    u16* __restrict__ XAll, const int* __restrict__ flagp)
{
  const int F = *flagp;
  const int ib = blockIdx.x;          // 0..3071
  const int i = ib >> 6, b = ib & 63;
  u16* xr = XAll + (size_t)ib * 1024;
  const int fa = father_idx[b * T_ + i];
  const int wa = word_idx[b * T_ + fa];
  const int use_f = (i > 0 && ((i - 1) % 3 != 0));
  const int wf = (i > 0) ? word_idx[b * T_ + (i - 1)] : 0;
  for (int rep = 0; rep < 2; ++rep) {
    int c = threadIdx.x + rep * 256;
    xr[c] = (i == 0) ? f2b(fc_emb[b * E_ + c])
                     : f2b(ldf(embed_tab, (size_t)wa * E_ + c, F));
    xr[512 + c] = use_f ? f2b(ldf(embed_tab, (size_t)wf * E_ + c, F)) : (u16)0;
  }
}

__global__ __launch_bounds__(256) void pack_bias(
    const void* bH, const void* bI, const void* bf1, const void* bf2,
    const void* bha, const void* bhf, const void* batt, const void* bfc,
    const void* blogit, const void* Walpha,
    float* biasComb, float* batt_f, float* bfc_f, float* blogit_f,
    float* walpha_f, const int* __restrict__ flagp)
{
  const int F = *flagp;
  int t = blockIdx.x * 256 + threadIdx.x;
  if (t < 1024) biasComb[t] = ldf(bH, t, F);
  else if (t < 1536) biasComb[t] = ldf(bI, t - 1024, F);
  else if (t < 2048) biasComb[t] = ldf(bf1, t - 1536, F);
  else if (t < 2560) biasComb[t] = ldf(bf2, t - 2048, F);
  if (t < 512) {
    biasComb[2560 + t] = ldf(bha, t, F) + ldf(bhf, t, F);
    batt_f[t] = ldf(batt, t, F);
    bfc_f[t] = ldf(bfc, t, F);
    walpha_f[t] = ldf(Walpha, t, F);
  }
  if (t < V_) blogit_f[t] = ldf(blogit, t, F);
}

// uniform-weight mean over a (196) of att_proj -> outc[b, seg*64 + lane]
__global__ __launch_bounds__(256) void att_apply_kernel(
    const float* __restrict__ alog, const u16* __restrict__ att_proj,
    float* __restrict__ outc)
{
  int b = blockIdx.x, seg = blockIdx.y, tid = threadIdx.x;
  __shared__ float sw[ATT_];
  __shared__ float rb[256];
  if (alog) {
    float l = (tid < ATT_) ? alog[b * ATT_ + tid] : -3.0e38f;
    rb[tid] = l; __syncthreads();
    for (int s = 128; s; s >>= 1) { if (tid < s) rb[tid] = fmaxf(rb[tid], rb[tid + s]); __syncthreads(); }
    float mx = rb[0]; __syncthreads();
    float e = (tid < ATT_) ? __expf(l - mx) : 0.f;
    rb[tid] = e; __syncthreads();
    for (int s = 128; s; s >>= 1) { if (tid < s) rb[tid] += rb[tid + s]; __syncthreads(); }
    float sum = rb[0]; __syncthreads();
    if (tid < ATT_) sw[tid] = e / sum;
  } else {
    if (tid < ATT_) sw[tid] = 1.f / (float)ATT_;
  }
  __syncthreads();
  int lane = tid & 63, g = tid >> 6;
  int col = seg * 64 + lane;
  float acc = 0.f;
  for (int a = g; a < ATT_; a += 4)
    acc += sw[a] * b2f(att_proj[(size_t)(b * ATT_ + a) * H_ + col]);
  rb[tid] = acc; __syncthreads();
  if (g == 0) outc[b * H_ + col] = rb[lane] + rb[64 + lane] + rb[128 + lane] + rb[192 + lane];
}

// in-place log_softmax over V=10000 per row of d_out (f32)
__global__ __launch_bounds__(256) void logsoftmax_kernel(float* __restrict__ out)
{
  __shared__ float vals[V_];
  __shared__ float rb[256];
  int row = blockIdx.x, tid = threadIdx.x;
  float* p = out + (size_t)row * V_;
  float mx = -3.0e38f;
  for (int c = tid * 4; c < V_; c += 1024) {
    float4 q = *(const float4*)(p + c);
    vals[c] = q.x; vals[c + 1] = q.y; vals[c + 2] = q.z; vals[c + 3] = q.w;
    mx = fmaxf(mx, fmaxf(fmaxf(q.x, q.y), fmaxf(q.z, q.w)));
  }
  rb[tid] = mx; __syncthreads();
  for (int s = 128; s; s >>= 1) { if (tid < s) rb[tid] = fmaxf(rb[tid], rb[tid + s]); __syncthreads(); }
  mx = rb[0]; __syncthreads();
  float sum = 0.f;
  for (int c = tid; c < V_; c += 256) sum += __expf(vals[c] - mx);
  rb[tid] = sum; __syncthreads();
  for (int s = 128; s; s >>= 1) { if (tid < s) rb[tid] += rb[tid + s]; __syncthreads(); }
  float lse = mx + __logf(rb[0]);
  for (int c = tid * 4; c < V_; c += 1024) {
    float4 q;
    q.x = vals[c] - lse; q.y = vals[c + 1] - lse;
    q.z = vals[c + 2] - lse; q.w = vals[c + 3] - lse;
    *(float4*)(p + c) = q;
  }
}

extern "C" void kernel_launch(void* const* d_in, const int* in_sizes, int n_in,
                              void* d_out, int out_size, void* d_ws, size_t ws_size,
                              hipStream_t stream)
{
  const int* word_idx   = (const int*)d_in[0];
  const int* father_idx = (const int*)d_in[1];
  const void* fc_feats  = d_in[2];
  const void* att_feats = d_in[3];
  const void* W_fc      = d_in[4];
  const void* b_fc      = d_in[5];
  const void* W_att     = d_in[6];
  const void* b_att     = d_in[7];
  const void* embed_tab = d_in[8];
  const void* weight_f1 = d_in[9];
  const void* bias_f1   = d_in[10];
  const void* weight_f2 = d_in[11];
  const void* bias_f2   = d_in[12];
  const void* weight_H  = d_in[13];
  const void* bias_H    = d_in[14];
  const void* weight_I  = d_in[15];
  const void* bias_I    = d_in[16];
  const void* W_ha      = d_in[17];
  const void* b_ha      = d_in[18];
  const void* W_hf      = d_in[19];
  const void* b_hf      = d_in[20];
  const void* W_alpha   = d_in[21];
  const void* b_alpha   = d_in[22];   // unused: softmax is shift-invariant
  const void* W_logit   = d_in[23];
  const void* b_logit   = d_in[24];
  (void)b_alpha;

  // ---- d_out (122.88 MB) hosts all dead-before-logits scratch -------------
  char* dob = (char*)d_out;
  size_t doff = 0;
  auto oalloc = [&](size_t bytes) -> char* {
    char* p = dob + doff;
    doff += (bytes + 255) & ~(size_t)255;
    return p;
  };
  u16*  p_att    = (u16*)oalloc((size_t)B_ * ATT_ * E_ * 2);    // 12.85 MB
  u16*  att_proj = (u16*)oalloc((size_t)B_ * ATT_ * H_ * 2);    // 12.85 MB
  u16*  att_bf16 = (u16*)oalloc((size_t)B_ * ATT_ * AF_ * 2);   // 51.38 MB
  float* Gx       = (float*)att_bf16;   // 31.46 MB alias: dead after att GEMMs
  u16*  WstepX   = (u16*)oalloc((size_t)2560 * 1024 * 2);       //  5.24 MB
  u16*  Wcomb    = (u16*)oalloc((size_t)GB_N * 1024 * 2);       //  6.29 MB
  u16*  XAll     = (u16*)oalloc((size_t)B_ * T_ * 1024 * 2);    //  6.29 MB
  float* c_states = (float*)oalloc((size_t)B_ * T_ * H_ * 4);   //  6.29 MB
  float* GbufA    = (float*)oalloc((size_t)2 * B_ * GB_N * 4);  //  1.57 MB
  float* GbufB    = (float*)oalloc((size_t)2 * B_ * GB_N * 4);  //  1.57 MB
  u16*  hcat     = (u16*)oalloc((size_t)B_ * 1024 * 2);         //  0.13 MB
  float* fc_emb   = (float*)oalloc((size_t)B_ * E_ * 4);
  float* att_meanp= (float*)oalloc((size_t)B_ * H_ * 4);
  float* biasComb = (float*)oalloc(GB_N * 4);
  float* batt_f   = (float*)oalloc(512 * 4);
  float* bfc_f    = (float*)oalloc(512 * 4);
  float* walpha_f = (float*)oalloc(512 * 4);
  // total ~105 MB < 122.88 MB ✓

  // ---- only buffers LIVE during the final logits GEMM go in d_ws ----------
  char* ws = (char*)d_ws;
  size_t woff = 0;
  auto walloc = [&](size_t bytes) -> char* {
    char* p = ws + woff;
    woff += (bytes + 255) & ~(size_t)255;
    return p;
  };
  u16*  houts     = (u16*)walloc((size_t)B_ * T_ * H_ * 2);     // 3.15 MB
  float* blogit_f = (float*)walloc((size_t)V_ * 4);
  int*   flag     = (int*)walloc(256);
  int*   barws    = (int*)walloc(256);

  hipMemsetAsync(c_states, 0, (size_t)B_ * T_ * H_ * 4, stream);
  hipMemsetAsync(houts, 0, (size_t)B_ * T_ * H_ * 2, stream);
  hipMemsetAsync(barws, 0, 256, stream);

  detect_f32<<<1, 256, 0, stream>>>((const u16*)att_feats, flag);

  pack_wstep<<<4096, 256, 0, stream>>>(weight_H, weight_I, weight_f1, weight_f2,
                                       WstepX, Wcomb, flag);
  pack_whahf<<<2048, 256, 0, stream>>>(W_ha, W_hf, Wcomb, flag);
  pack_attf<<<4096, 256, 0, stream>>>(att_feats, att_bf16, flag);
  pack_bias<<<40, 256, 0, stream>>>(bias_H, bias_I, bias_f1, bias_f2, b_ha, b_hf,
                                    b_att, b_fc, b_logit, W_alpha,
                                    biasComb, batt_f, bfc_f, blogit_f,
                                    walpha_f, flag);

  // fc_emb = fc_feats @ W_fc^T + b_fc  (f32 out)
  gemm_nt<float><<<dim3(1, 8, 1), 256, 0, stream>>>(
      fc_feats, FC_, 0, MD_DYN, W_fc, FC_, 0, MD_DYN,
      fc_emb, E_, E_, FC_, bfc_f, 0, flag);
  pack_xall<<<B_ * T_, 256, 0, stream>>>(fc_emb, embed_tab, word_idx, father_idx,
                                         XAll, flag);
  // p_att = att_feats @ W_att^T + b_att  (bf16 A, bf16 out)
  gemm_nt<u16><<<dim3(B_ * ATT_ / 64, 8, 1), 256, 0, stream>>>(
      att_bf16, AF_, 0, MD_BF16, W_att, AF_, 0, MD_DYN,
      p_att, E_, E_, AF_, batt_f, 0, flag);
  // att_proj = att_feats @ weight_I[:, 2048:4096]^T  (bf16 A, bf16 out)
  gemm_nt<u16><<<dim3(B_ * ATT_ / 64, 8, 1), 256, 0, stream>>>(
      att_bf16, AF_, 0, MD_BF16, weight_I, 4096, 2048, MD_DYN,
      att_proj, H_, H_, AF_, nullptr, 0, flag);
  // Gx = XAll @ WstepX^T  (x-half of all 48 step-GEMMs, hoisted; bias lives
  // in the per-step GEMM z0). OVERWRITES att_bf16 (dead after att GEMMs).
  gemm_nt<float><<<dim3(B_ * T_ / 64, 2560 / 64, 1), 256, 0, stream>>>(
      XAll, 1024, 0, MD_BF16, WstepX, 1024, 0, MD_BF16,
      Gx, 2560, 2560, 1024, nullptr, 0, flag);
  // att_mean contribution = mean_a att_proj
  att_apply_kernel<<<dim3(B_, 8), 256, 0, stream>>>(nullptr, att_proj, att_meanp);

  // Gbuf for step 0: h inputs zero -> z0 = bias, z1 = 0
  ginit<<<(B_ * GB_N) / 512, 512, 0, stream>>>(GbufA, biasComb);

  // ---- T=48 loop: ONE kernel per step (internal att->GEMM sync) -----------
  float* Gp = GbufA;
  float* Gn = GbufB;
  for (int i = 0; i < T_; ++i) {
    step_full<<<112, 512, 0, stream>>>(
        Gp, Gn, p_att, walpha_f, att_proj, att_meanp, Gx,
        c_states, houts, hcat, father_idx, Wcomb, biasComb,
        barws, 64 * (i + 1), i);
    float* t = Gp; Gp = Gn; Gn = t;
  }

  // logits = houts @ W_logit^T + b_logit -> d_out (f32), XCD-chunked tiles,
  // then in-place log_softmax.
  gemm_logit<<<48 * 160, 256, 0, stream>>>(houts, W_logit, (float*)d_out,
                                           blogit_f, flag);
  logsoftmax_kernel<<<B_ * T_, 256, 0, stream>>>((float*)d_out);
}

// Round 9
// 2811.890 us; speedup vs baseline: 3.6101x; 1.0631x over previous
//
#include <hip/hip_runtime.h>
#include <hip/hip_bf16.h>
#include <type_traits>

#define B_   64
#define T_   48
#define H_   512
#define E_   512
#define ATT_ 196
#define AF_  2048
#define FC_  2048
#define V_   10000
#define GB_N 3072   // gates (2560) + tat (512) output columns

typedef unsigned short u16;
typedef unsigned int u32;
typedef unsigned long long u64;
using s16x8 = __attribute__((ext_vector_type(8))) short;
using f32x4 = __attribute__((ext_vector_type(4))) float;

// input-storage modes for GEMM/pointwise loaders
#define MD_BF16 0
#define MD_F32  1
#define MD_DYN  2   // resolve from detected flag (d_in float tensors)

__device__ __forceinline__ float b2f(u16 u) {
  union { unsigned int i; float f; } x; x.i = ((unsigned int)u) << 16; return x.f;
}
__device__ __forceinline__ u16 f2b(float f) {
  union { float f; unsigned int i; } x; x.f = f;
  unsigned int r = x.i + 0x7fffu + ((x.i >> 16) & 1u);
  return (u16)(r >> 16);
}
__device__ __forceinline__ float sigmoid_(float x) { return 1.f / (1.f + __expf(-x)); }
__device__ __forceinline__ float tanh_(float x) { return 1.f - 2.f / (__expf(2.f * x) + 1.f); }

__device__ __forceinline__ float ldf(const void* p, size_t i, int f) {
  return f ? ((const float*)p)[i] : b2f(((const u16*)p)[i]);
}
__device__ __forceinline__ s16x8 ld8(const void* p, size_t idx, int f) {
  s16x8 r;
  if (f) {
    const float* q = (const float*)p + idx;
    float4 x = *(const float4*)q;
    float4 y = *(const float4*)(q + 4);
    r[0] = (short)f2b(x.x); r[1] = (short)f2b(x.y);
    r[2] = (short)f2b(x.z); r[3] = (short)f2b(x.w);
    r[4] = (short)f2b(y.x); r[5] = (short)f2b(y.y);
    r[6] = (short)f2b(y.z); r[7] = (short)f2b(y.w);
  } else {
    r = *(const s16x8*)((const u16*)p + idx);
  }
  return r;
}
__device__ __forceinline__ s16x8 zero8() {
  s16x8 r; for (int j = 0; j < 8; j++) r[j] = 0; return r;
}

// ---- agent-scope relaxed atomics (proven rounds 4-8): device-coherent via
// coherence point. Used ONLY for the 128 KB hcat crossing the intra-kernel
// producer->consumer boundary.
__device__ __forceinline__ u64 aload_u64(const u64* p) {
  return __hip_atomic_load(p, __ATOMIC_RELAXED, __HIP_MEMORY_SCOPE_AGENT);
}
__device__ __forceinline__ void astore_u32(u32* p, u32 v) {
  __hip_atomic_store(p, v, __ATOMIC_RELAXED, __HIP_MEMORY_SCOPE_AGENT);
}
__device__ __forceinline__ s16x8 ld8_coh(const u16* p) {
  union { u64 u[2]; s16x8 v; } x;
  x.u[0] = aload_u64((const u64*)p);
  x.u[1] = aload_u64((const u64*)p + 1);
  return x.v;
}

// storage detector: f32 storage => u16 view of att_feats contains exponent-0xFF
// bit patterns (random mantissa halves) with certainty; bf16 N(0,1) never does.
__global__ void detect_f32(const u16* __restrict__ p, int* __restrict__ flag) {
  __shared__ int sb[256];
  int t = threadIdx.x, bad = 0;
  for (int i = t; i < 65536; i += 256) {
    int e = (p[i] >> 7) & 0xFF;
    bad |= (e == 0xFF) ? 1 : 0;
  }
  sb[t] = bad; __syncthreads();
  for (int s = 128; s; s >>= 1) { if (t < s) sb[t] |= sb[t + s]; __syncthreads(); }
  if (t == 0) *flag = sb[0];
}

// ---------------------------------------------------------------------------
// NT GEMM (small one-time GEMMs): C[MxN] = A[MxK] * B[NxK]^T (+bias).
// ---------------------------------------------------------------------------
template <typename CT>
__global__ __launch_bounds__(256) void gemm_nt(
    const void* __restrict__ A, int lda, size_t aoff, int amode,
    const void* __restrict__ B, int ldb, size_t boff, int bmode,
    CT* __restrict__ C, int ldc, int N, int Kc,
    const float* __restrict__ bias, size_t zstride, const int* __restrict__ flagp)
{
  __shared__ __align__(16) u16 As[64 * 40];
  __shared__ __align__(16) u16 Bs[64 * 40];

  const int dynf = *flagp;
  const int aF = (amode == MD_DYN) ? dynf : amode;
  const int bF = (bmode == MD_DYN) ? dynf : bmode;

  const int tid  = threadIdx.x;
  const int m0   = blockIdx.x * 64;
  const int n0   = blockIdx.y * 64;
  const int kz   = blockIdx.z * Kc;
  const int lane = tid & 63;
  const int w    = tid >> 6;
  const int wm   = (w >> 1) * 32;
  const int wn   = (w & 1) * 32;
  const int quad = lane >> 4;
  const int r16  = lane & 15;

  f32x4 acc[2][2];
  for (int a = 0; a < 2; a++) for (int b = 0; b < 2; b++)
    for (int k = 0; k < 4; k++) acc[a][b][k] = 0.f;

  const int sr = tid >> 2;
  const int sc = (tid & 3) * 8;
  const size_t idxA = (size_t)(m0 + sr) * lda + aoff + kz + sc;
  const size_t idxB = (size_t)(n0 + sr) * ldb + boff + kz + sc;
  const bool bok = (n0 + sr) < N;

  const int aoff0 = (wm + r16) * 40 + quad * 8;
  const int aoff1 = (wm + 16 + r16) * 40 + quad * 8;
  const int boff0 = (wn + r16) * 40 + quad * 8;
  const int boff1 = (wn + 16 + r16) * 40 + quad * 8;

  s16x8 av = ld8(A, idxA, aF);
  s16x8 bv = bok ? ld8(B, idxB, bF) : zero8();

  for (int k0 = 0; k0 < Kc; k0 += 32) {
    s16x8 avn = zero8(), bvn = zero8();
    if (k0 + 32 < Kc) {
      avn = ld8(A, idxA + k0 + 32, aF);
      if (bok) bvn = ld8(B, idxB + k0 + 32, bF);
    }
    __syncthreads();
    *(s16x8*)(As + sr * 40 + sc) = av;
    *(s16x8*)(Bs + sr * 40 + sc) = bv;
    __syncthreads();
    s16x8 a0 = *(const s16x8*)(As + aoff0);
    s16x8 a1 = *(const s16x8*)(As + aoff1);
    s16x8 b0 = *(const s16x8*)(Bs + boff0);
    s16x8 b1 = *(const s16x8*)(Bs + boff1);
    acc[0][0] = __builtin_amdgcn_mfma_f32_16x16x32_bf16(a0, b0, acc[0][0], 0, 0, 0);
    acc[0][1] = __builtin_amdgcn_mfma_f32_16x16x32_bf16(a0, b1, acc[0][1], 0, 0, 0);
    acc[1][0] = __builtin_amdgcn_mfma_f32_16x16x32_bf16(a1, b0, acc[1][0], 0, 0, 0);
    acc[1][1] = __builtin_amdgcn_mfma_f32_16x16x32_bf16(a1, b1, acc[1][1], 0, 0, 0);
    av = avn; bv = bvn;
  }

  CT* Cz = C + (size_t)blockIdx.z * zstride;
  const bool addb = (bias != nullptr) && (blockIdx.z == 0);
  for (int tm = 0; tm < 2; tm++)
    for (int tn = 0; tn < 2; tn++) {
      int col = n0 + wn + tn * 16 + r16;
      if (col >= N) continue;
      float bb = addb ? bias[col] : 0.f;
      int rowbase = m0 + wm + tm * 16 + quad * 4;
      for (int rg = 0; rg < 4; rg++) {
        float v = acc[tm][tn][rg] + bb;
        if constexpr (std::is_same<CT, float>::value)
          Cz[(size_t)(rowbase + rg) * ldc + col] = v;
        else
          Cz[(size_t)(rowbase + rg) * ldc + col] = f2b(v);
      }
    }
}

// ---------------------------------------------------------------------------
// 64x128-tile, 8-wave NT GEMM (bf16 A,B), streaming A/B slabs (BK=32).
// Wave layout identical to step_full's proven GEMM section.
// grid: (N/128, M/64). Optional column-split output: if C2 != null, cols
// >= 512 go to C2 at col-512 (used by the fused p_att|att_proj GEMM).
// bias indexed by global col (pass zeros where no bias), or nullptr.
// ---------------------------------------------------------------------------
template <typename CT>
__global__ __launch_bounds__(512) void gemm_nt128(
    const u16* __restrict__ A, int lda,
    const u16* __restrict__ B, int ldb,
    CT* __restrict__ C, CT* __restrict__ C2, int ldc,
    int Kc, const float* __restrict__ bias)
{
  __shared__ __align__(16) u16 As[64 * 40];
  __shared__ __align__(16) u16 Bs[128 * 40];

  const int tid = threadIdx.x;
  const int n0 = blockIdx.x * 128;
  const int m0 = blockIdx.y * 64;
  const int lane = tid & 63;
  const int w    = tid >> 6;
  const int wm   = (w & 1) * 32;
  const int wn   = (w >> 1) * 32;
  const int quad = lane >> 4;
  const int r16  = lane & 15;

  f32x4 acc[2][2];
#pragma unroll
  for (int a = 0; a < 2; a++)
#pragma unroll
    for (int c = 0; c < 2; c++)
#pragma unroll
      for (int k = 0; k < 4; k++) acc[a][c][k] = 0.f;

  const int srA = (tid & 255) >> 2;   // 0..63
  const int scA = (tid & 3) * 8;
  const int srB = tid >> 2;           // 0..127
  const int scB = (tid & 3) * 8;
  const u16* pa = A + (size_t)(m0 + srA) * lda + scA;
  const u16* pb = B + (size_t)(n0 + srB) * ldb + scB;

  const int ao0 = (wm + r16) * 40 + quad * 8;
  const int ao1 = (wm + 16 + r16) * 40 + quad * 8;
  const int bo0 = (wn + r16) * 40 + quad * 8;
  const int bo1 = (wn + 16 + r16) * 40 + quad * 8;

  s16x8 av = zero8(), bv;
  if (tid < 256) av = *(const s16x8*)pa;
  bv = *(const s16x8*)pb;

  for (int k0 = 0; k0 < Kc; k0 += 32) {
    s16x8 avn = zero8(), bvn = zero8();
    if (k0 + 32 < Kc) {
      if (tid < 256) avn = *(const s16x8*)(pa + k0 + 32);
      bvn = *(const s16x8*)(pb + k0 + 32);
    }
    __syncthreads();
    if (tid < 256) *(s16x8*)(As + srA * 40 + scA) = av;
    *(s16x8*)(Bs + srB * 40 + scB) = bv;
    __syncthreads();
    s16x8 a0 = *(const s16x8*)(As + ao0);
    s16x8 a1 = *(const s16x8*)(As + ao1);
    s16x8 b0 = *(const s16x8*)(Bs + bo0);
    s16x8 b1 = *(const s16x8*)(Bs + bo1);
    acc[0][0] = __builtin_amdgcn_mfma_f32_16x16x32_bf16(a0, b0, acc[0][0], 0, 0, 0);
    acc[0][1] = __builtin_amdgcn_mfma_f32_16x16x32_bf16(a0, b1, acc[0][1], 0, 0, 0);
    acc[1][0] = __builtin_amdgcn_mfma_f32_16x16x32_bf16(a1, b0, acc[1][0], 0, 0, 0);
    acc[1][1] = __builtin_amdgcn_mfma_f32_16x16x32_bf16(a1, b1, acc[1][1], 0, 0, 0);
    av = avn; bv = bvn;
  }

#pragma unroll
  for (int tm = 0; tm < 2; tm++)
#pragma unroll
    for (int tn = 0; tn < 2; tn++) {
      int col = n0 + wn + tn * 16 + r16;
      float bb = bias ? bias[col] : 0.f;
      CT* Ct = C; int ccol = col;
      if (C2 != nullptr && col >= 512) { Ct = C2; ccol = col - 512; }
      int rowbase = m0 + wm + tm * 16 + quad * 4;
#pragma unroll
      for (int rg = 0; rg < 4; rg++) {
        float v = acc[tm][tn][rg] + bb;
        if constexpr (std::is_same<CT, float>::value)
          Ct[(size_t)(rowbase + rg) * ldc + ccol] = v;
        else
          Ct[(size_t)(rowbase + rg) * ldc + ccol] = f2b(v);
      }
    }
}

// ---------------------------------------------------------------------------
// Logits GEMM with XCD-chunked N-tiling (round-8 proven).
// ---------------------------------------------------------------------------
__global__ __launch_bounds__(256) void gemm_logit(
    const u16* __restrict__ A, const void* __restrict__ B,
    float* __restrict__ C, const float* __restrict__ bias,
    const int* __restrict__ flagp)
{
  __shared__ __align__(16) u16 As[64 * 40];
  __shared__ __align__(16) u16 Bs[64 * 40];

  const int bF = *flagp;
  const int bid = blockIdx.x;
  const int xcd = bid & 7, rest = bid >> 3;
  const int yl = rest % 20, xt = rest / 20;
  const int m0 = xt * 64;
  const int n0 = (xcd * 20 + yl) * 64;

  const int tid  = threadIdx.x;
  const int lane = tid & 63;
  const int w    = tid >> 6;
  const int wm   = (w >> 1) * 32;
  const int wn   = (w & 1) * 32;
  const int quad = lane >> 4;
  const int r16  = lane & 15;

  f32x4 acc[2][2];
  for (int a = 0; a < 2; a++) for (int b = 0; b < 2; b++)
    for (int k = 0; k < 4; k++) acc[a][b][k] = 0.f;

  const int sr = tid >> 2;
  const int sc = (tid & 3) * 8;
  const u16* pa = A + (size_t)(m0 + sr) * 512 + sc;
  const size_t idxB = (size_t)(n0 + sr) * 512 + sc;
  const bool bok = (n0 + sr) < V_;

  const int ao0 = (wm + r16) * 40 + quad * 8;
  const int ao1 = (wm + 16 + r16) * 40 + quad * 8;
  const int bo0 = (wn + r16) * 40 + quad * 8;
  const int bo1 = (wn + 16 + r16) * 40 + quad * 8;

  s16x8 av = *(const s16x8*)pa;
  s16x8 bv = bok ? ld8(B, idxB, bF) : zero8();

  for (int k0 = 0; k0 < 512; k0 += 32) {
    s16x8 avn = zero8(), bvn = zero8();
    if (k0 + 32 < 512) {
      avn = *(const s16x8*)(pa + k0 + 32);
      if (bok) bvn = ld8(B, idxB + k0 + 32, bF);
    }
    __syncthreads();
    *(s16x8*)(As + sr * 40 + sc) = av;
    *(s16x8*)(Bs + sr * 40 + sc) = bv;
    __syncthreads();
    s16x8 a0 = *(const s16x8*)(As + ao0);
    s16x8 a1 = *(const s16x8*)(As + ao1);
    s16x8 b0 = *(const s16x8*)(Bs + bo0);
    s16x8 b1 = *(const s16x8*)(Bs + bo1);
    acc[0][0] = __builtin_amdgcn_mfma_f32_16x16x32_bf16(a0, b0, acc[0][0], 0, 0, 0);
    acc[0][1] = __builtin_amdgcn_mfma_f32_16x16x32_bf16(a0, b1, acc[0][1], 0, 0, 0);
    acc[1][0] = __builtin_amdgcn_mfma_f32_16x16x32_bf16(a1, b0, acc[1][0], 0, 0, 0);
    acc[1][1] = __builtin_amdgcn_mfma_f32_16x16x32_bf16(a1, b1, acc[1][1], 0, 0, 0);
    av = avn; bv = bvn;
  }

  for (int tm = 0; tm < 2; tm++)
    for (int tn = 0; tn < 2; tn++) {
      int col = n0 + wn + tn * 16 + r16;
      if (col >= V_) continue;
      float bb = bias[col];
      int rowbase = m0 + wm + tm * 16 + quad * 4;
      for (int rg = 0; rg < 4; rg++)
        C[(size_t)(rowbase + rg) * V_ + col] = acc[tm][tn][rg] + bb;
    }
}

// Gbuf init for step 0: h inputs are zero => gates = bias (z0), 0 (z1)
__global__ __launch_bounds__(512) void ginit(float* __restrict__ G,
                                             const float* __restrict__ biasComb)
{
  const size_t idx = (size_t)blockIdx.x * 512 + threadIdx.x;   // < 64*3072
  const int c = (int)(idx % GB_N);
  G[idx] = biasComb[c];
  G[(size_t)B_ * GB_N + idx] = 0.f;
}

// ---------------------------------------------------------------------------
// MERGED per-step kernel (round-8 proven; attention loops MLP-deepened).
// ---------------------------------------------------------------------------
__global__ __launch_bounds__(512) void step_full(
    const float* __restrict__ Gprev, float* __restrict__ Gnext,
    const u16* __restrict__ p_att, const float* __restrict__ walpha_f,
    const u16* __restrict__ att_proj, const float* __restrict__ att_meanp,
    const float* __restrict__ Gx,
    float* __restrict__ c_states, u16* __restrict__ houts,
    u16* __restrict__ hcat, const int* __restrict__ father_idx,
    const u16* __restrict__ Wcomb, const float* __restrict__ biasComb,
    int* __restrict__ barcnt, int btarget, int i)
{
  const int blk = blockIdx.x, tid = threadIdx.x;
  const int lane = tid & 63, w = tid >> 6;
  const size_t zs = (size_t)B_ * GB_N;

  if (blk < 64) {
    // ======================= attention + finish =======================
    __shared__ float tat_sh[512];
    __shared__ float sl[256];
    __shared__ float red[512];
    __shared__ u16 nh_sh[512];
    __shared__ u16 ha_sh[512];

    const int b = blk;
    const int is_first = (i == 0);
    const int use_f = (!is_first) && ((i - 1) % 3 != 0);

    // early independent loads (hide latency under attention)
    const float* Gb = Gprev + (size_t)b * GB_N + tid;
    float g0 = Gb[0]    + Gb[zs];
    float g1 = Gb[512]  + Gb[zs + 512];
    float g2 = Gb[1024] + Gb[zs + 1024];
    float g3 = Gb[1536] + Gb[zs + 1536];
    float g4 = Gb[2048] + Gb[zs + 2048];
    const float* gx = Gx + ((size_t)i * B_ + b) * 2560 + tid;
    float gx0 = gx[0], gx1 = gx[512], gx2 = gx[1024];
    float gx3 = gx[1536], gx4 = gx[2048];

    float attv;
    if (is_first) {
      attv = att_meanp[b * H_ + tid];
    } else {
      tat_sh[tid] = Gb[2560] + Gb[zs + 2560];   // bias (bhahf) already in z0
      __syncthreads();
      // logits: wave w -> a = w, w+8, ...; 2-deep p_att row prefetch
      {
        float t8[8], wa8[8];
#pragma unroll
        for (int j = 0; j < 8; j++) {
          t8[j]  = tat_sh[lane * 8 + j];
          wa8[j] = walpha_f[lane * 8 + j];
        }
        const u16* pb = p_att + (size_t)b * ATT_ * 512 + lane * 8;
        s16x8 pv0 = *(const s16x8*)(pb + (size_t)w * 512);
        s16x8 pv1 = *(const s16x8*)(pb + (size_t)(w + 8) * 512);
        for (int a = w; a < ATT_; a += 8) {
          s16x8 nx = zero8();
          if (a + 16 < ATT_) nx = *(const s16x8*)(pb + (size_t)(a + 16) * 512);
          float acc = 0.f;
#pragma unroll
          for (int j = 0; j < 8; j++)
            acc += wa8[j] * tanh_(t8[j] + b2f((u16)pv0[j]));
#pragma unroll
          for (int off = 32; off; off >>= 1) acc += __shfl_down(acc, off);
          if (lane == 0) sl[a] = acc;
          pv0 = pv1; pv1 = nx;
        }
      }
      __syncthreads();
      // softmax over 196 logits
      float l = (tid < ATT_) ? sl[tid] : -3.0e38f;
      red[tid] = l; __syncthreads();
      for (int s = 256; s; s >>= 1) { if (tid < s) red[tid] = fmaxf(red[tid], red[tid + s]); __syncthreads(); }
      float mx = red[0]; __syncthreads();
      float e = (tid < ATT_) ? __expf(l - mx) : 0.f;
      red[tid] = e; __syncthreads();
      for (int s = 256; s; s >>= 1) { if (tid < s) red[tid] += red[tid + s]; __syncthreads(); }
      float inv = 1.f / red[0];
      __syncthreads();
      if (tid < ATT_) sl[tid] = e * inv;
      __syncthreads();
      // apply: attv = sum_a w[a] * att_proj[b,a,tid] (8-way MLP)
      {
        const u16* ap = att_proj + (size_t)b * ATT_ * 512 + tid;
        float ac[8];
#pragma unroll
        for (int j = 0; j < 8; j++) ac[j] = 0.f;
        for (int a = 0; a < 192; a += 8) {
#pragma unroll
          for (int j = 0; j < 8; j++)
            ac[j] += sl[a + j] * b2f(ap[(size_t)(a + j) * 512]);
        }
#pragma unroll
        for (int j = 0; j < 4; j++)
          ac[j] += sl[192 + j] * b2f(ap[(size_t)(192 + j) * 512]);
        attv = ((ac[0] + ac[1]) + (ac[2] + ac[3])) +
               ((ac[4] + ac[5]) + (ac[6] + ac[7]));
      }
    }

    // ---- LSTM finish (thread tid owns element tid of batch b) ----
    float ing  = sigmoid_(g0 + gx0);
    float outg = sigmoid_(g1 + gx1);
    float cg   = tanh_(g2 + gx2 + attv);
    float f1   = sigmoid_(g3 + gx3);
    float f2   = sigmoid_(g4 + gx4);
    const int father = father_idx[b * T_ + i];
    // father==i (or future) reads the memset zeros, matching reference scan
    float c1 = is_first ? 0.f : c_states[((size_t)b * T_ + father) * H_ + tid];
    float c2 = use_f ? c_states[((size_t)b * T_ + (i - 1)) * H_ + tid] : 0.f;
    float nc = f1 * c1 + f2 * c2 + ing * cg;
    float nh = outg * tanh_(nc);
    size_t o = ((size_t)b * T_ + i) * H_ + tid;
    c_states[o] = nc;
    u16 hb = f2b(nh);
    houts[o] = hb;
    if (i + 1 < T_) {
      const int fn = father_idx[b * T_ + (i + 1)];
      const int use_fn = (i % 3 != 0);
      nh_sh[tid] = hb;
      // h_a: fn==i -> just-computed nh; fn>i -> memset zeros; fn<i -> prior
      ha_sh[tid] = (fn == i) ? hb : houts[((size_t)b * T_ + fn) * H_ + tid];
      __syncthreads();
      if (tid < 256) {
        u32 aw = (u32)ha_sh[2 * tid] | ((u32)ha_sh[2 * tid + 1] << 16);
        u32 fw = use_fn ? ((u32)nh_sh[2 * tid] | ((u32)nh_sh[2 * tid + 1] << 16)) : 0u;
        astore_u32((u32*)(hcat + (size_t)b * 1024) + tid, aw);
        astore_u32((u32*)(hcat + (size_t)b * 1024 + 512) + tid, fw);
      }
    }
    // drain hcat stores, then count in (monotonic counter, no reset)
    asm volatile("s_waitcnt vmcnt(0)" ::: "memory");
    __syncthreads();
    if (tid == 0)
      __hip_atomic_fetch_add(barcnt, 1, __ATOMIC_RELAXED, __HIP_MEMORY_SCOPE_AGENT);
    return;
  }

  // ======================= gates+tat GEMM (step i+1) =======================
  if (i + 1 >= T_) return;
  __shared__ __align__(16) u16 As[64 * 40];
  __shared__ __align__(16) u16 Bs[128 * 40];

  const int g  = blk - 64;            // 0..47
  const int ny = g % 24, z = g / 24;  // 24 N-tiles (128 wide) x 2 split-K
  const int n0 = ny * 128, kz = z * 512;
  const int wm = (w & 1) * 32;
  const int wn = (w >> 1) * 32;
  const int quad = lane >> 4;
  const int r16  = lane & 15;

  // warm this block's Wcomb slab into L2 while attention runs
  {
    const u16* wb = Wcomb + (size_t)n0 * 1024 + kz;
    for (int l = tid; l < 1024; l += 512) {
      const volatile u32* pl =
          (const volatile u32*)(wb + (size_t)(l >> 3) * 1024 + (l & 7) * 64);
      (void)*pl;
    }
  }
  // wait for all 64 attention blocks of this step
  if (tid == 0) {
    while (__hip_atomic_load(barcnt, __ATOMIC_RELAXED, __HIP_MEMORY_SCOPE_AGENT) < btarget)
      __builtin_amdgcn_s_sleep(2);
  }
  __syncthreads();

  // A slab (hcat, device-coherent) -> registers, all loads issued up-front
  const int r  = tid & 255;
  const int sr = r >> 2;            // hcat row 0..63
  const int sc = (r & 3) * 8;
  s16x8 areg[16];
  if (tid < 256) {
    const u16* ap = hcat + (size_t)sr * 1024 + kz + sc;
#pragma unroll
    for (int it = 0; it < 16; ++it) areg[it] = ld8_coh(ap + it * 32);
  }
  const int br = tid >> 2;          // B row 0..127
  const int bc = (tid & 3) * 8;
  const u16* bp = Wcomb + (size_t)(n0 + br) * 1024 + kz + bc;

  f32x4 acc[2][2];
#pragma unroll
  for (int a = 0; a < 2; a++)
#pragma unroll
    for (int c = 0; c < 2; c++)
#pragma unroll
      for (int k = 0; k < 4; k++) acc[a][c][k] = 0.f;

  const int ao0 = (wm + r16) * 40 + quad * 8;
  const int ao1 = (wm + 16 + r16) * 40 + quad * 8;
  const int bo0 = (wn + r16) * 40 + quad * 8;
  const int bo1 = (wn + 16 + r16) * 40 + quad * 8;

  s16x8 bv = *(const s16x8*)bp;
#pragma unroll
  for (int it = 0; it < 16; ++it) {
    s16x8 bn = zero8();
    if (it + 1 < 16) bn = *(const s16x8*)(bp + (it + 1) * 32);
    __syncthreads();
    if (tid < 256) *(s16x8*)(As + sr * 40 + sc) = areg[it];
    *(s16x8*)(Bs + br * 40 + bc) = bv;
    __syncthreads();
    s16x8 a0 = *(const s16x8*)(As + ao0);
    s16x8 a1 = *(const s16x8*)(As + ao1);
    s16x8 b0 = *(const s16x8*)(Bs + bo0);
    s16x8 b1 = *(const s16x8*)(Bs + bo1);
    acc[0][0] = __builtin_amdgcn_mfma_f32_16x16x32_bf16(a0, b0, acc[0][0], 0, 0, 0);
    acc[0][1] = __builtin_amdgcn_mfma_f32_16x16x32_bf16(a0, b1, acc[0][1], 0, 0, 0);
    acc[1][0] = __builtin_amdgcn_mfma_f32_16x16x32_bf16(a1, b0, acc[1][0], 0, 0, 0);
    acc[1][1] = __builtin_amdgcn_mfma_f32_16x16x32_bf16(a1, b1, acc[1][1], 0, 0, 0);
    bv = bn;
  }

  float* Cz = Gnext + (size_t)z * zs;
#pragma unroll
  for (int tm = 0; tm < 2; tm++)
#pragma unroll
    for (int tn = 0; tn < 2; tn++) {
      int col = n0 + wn + tn * 16 + r16;
      float bb = (z == 0) ? biasComb[col] : 0.f;
      int row0 = wm + tm * 16 + quad * 4;
#pragma unroll
      for (int rg = 0; rg < 4; rg++)
        Cz[(size_t)(row0 + rg) * GB_N + col] = acc[tm][tn][rg] + bb;
    }
}

// --- weight/bias packing (reads d_in floats via flag) ------------------------
__global__ __launch_bounds__(256) void pack_wstep(
    const void* __restrict__ wH, const void* __restrict__ wI,
    const void* __restrict__ wf1, const void* __restrict__ wf2,
    u16* __restrict__ WstepX, u16* __restrict__ Wcomb,
    const int* __restrict__ flagp)
{
  const int F = *flagp;
  for (int idx = blockIdx.x * 256 + threadIdx.x; idx < 2560 * 2048; idx += gridDim.x * 256) {
    int row = idx >> 11, col = idx & 2047;
    float v = 0.f;
    if (row < 1024) v = ldf(wH, (size_t)row * 2048 + col, F);
    else if (row < 1536) v = ldf(wI, (size_t)(row - 1024) * 4096 + col, F);
    else if (row < 2048) {
      int r = row - 1536;
      if (col < 512) v = ldf(wf1, (size_t)r * 1024 + col, F);
      else if (col >= 1024 && col < 1536) v = ldf(wf1, (size_t)r * 1024 + 512 + (col - 1024), F);
    } else {
      int r = row - 2048;
      if (col >= 512 && col < 1024) v = ldf(wf2, (size_t)r * 1024 + (col - 512), F);
      else if (col >= 1536) v = ldf(wf2, (size_t)r * 1024 + 512 + (col - 1536), F);
    }
    if (col < 1024) WstepX[(size_t)row * 1024 + col] = f2b(v);
    else           Wcomb[(size_t)row * 1024 + (col - 1024)] = f2b(v);
  }
}

__global__ __launch_bounds__(256) void pack_whahf(
    const void* __restrict__ W_ha, const void* __restrict__ W_hf,
    u16* __restrict__ Wcomb, const int* __restrict__ flagp)
{
  const int F = *flagp;
  for (int idx = blockIdx.x * 256 + threadIdx.x; idx < 512 * 1024; idx += gridDim.x * 256) {
    int e = idx >> 10, k = idx & 1023;
    float v = (k < 512) ? ldf(W_ha, (size_t)e * 512 + k, F)
                        : ldf(W_hf, (size_t)e * 512 + (k - 512), F);
    Wcomb[(size_t)2560 * 1024 + idx] = f2b(v);
  }
}

// Wcat[1024][2048]: rows 0..511 = W_att, rows 512..1023 = weight_I[:,2048:4096]
__global__ __launch_bounds__(256) void pack_wcat(
    const void* __restrict__ W_att, const void* __restrict__ wI,
    u16* __restrict__ Wcat, const int* __restrict__ flagp)
{
  const int F = *flagp;
  for (int idx = blockIdx.x * 256 + threadIdx.x; idx < 1024 * 2048; idx += gridDim.x * 256) {
    int row = idx >> 11, col = idx & 2047;
    float v = (row < 512) ? ldf(W_att, (size_t)row * 2048 + col, F)
                          : ldf(wI, (size_t)(row - 512) * 4096 + 2048 + col, F);
    Wcat[idx] = f2b(v);
  }
}

// att_feats -> bf16 copy (zero numerical change: GEMMs already cast to bf16)
__global__ __launch_bounds__(256) void pack_attf(
    const void* __restrict__ src, u16* __restrict__ dst, const int* __restrict__ flagp)
{
  const int F = *flagp;
  const size_t n8 = (size_t)B_ * ATT_ * AF_ / 8;
  for (size_t idx = (size_t)blockIdx.x * 256 + threadIdx.x; idx < n8;
       idx += (size_t)gridDim.x * 256) {
    s16x8 v = ld8(src, idx * 8, F);
    *(s16x8*)(dst + idx * 8) = v;
  }
}

// XAll[i*64+b][0..1023] = [x_a | x_f] for step i, batch b (bf16)
__global__ __launch_bounds__(256) void pack_xall(
    const float* __restrict__ fc_emb, const void* __restrict__ embed_tab,
    const int* __restrict__ word_idx, const int* __restrict__ father_idx,
    u16* __restrict__ XAll, const int* __restrict__ flagp)
{
  const int F = *flagp;
  const int ib = blockIdx.x;          // 0..3071
  const int i = ib >> 6, b = ib & 63;
  u16* xr = XAll + (size_t)ib * 1024;
  const int fa = father_idx[b * T_ + i];
  const int wa = word_idx[b * T_ + fa];
  const int use_f = (i > 0 && ((i - 1) % 3 != 0));
  const int wf = (i > 0) ? word_idx[b * T_ + (i - 1)] : 0;
  for (int rep = 0; rep < 2; ++rep) {
    int c = threadIdx.x + rep * 256;
    xr[c] = (i == 0) ? f2b(fc_emb[b * E_ + c])
                     : f2b(ldf(embed_tab, (size_t)wa * E_ + c, F));
    xr[512 + c] = use_f ? f2b(ldf(embed_tab, (size_t)wf * E_ + c, F)) : (u16)0;
  }
}

__global__ __launch_bounds__(256) void pack_bias(
    const void* bH, const void* bI, const void* bf1, const void* bf2,
    const void* bha, const void* bhf, const void* batt, const void* bfc,
    const void* blogit, const void* Walpha,
    float* biasComb, float* biasCat, float* bfc_f, float* blogit_f,
    float* walpha_f, const int* __restrict__ flagp)
{
  const int F = *flagp;
  int t = blockIdx.x * 256 + threadIdx.x;
  if (t < 1024) biasComb[t] = ldf(bH, t, F);
  else if (t < 1536) biasComb[t] = ldf(bI, t - 1024, F);
  else if (t < 2048) biasComb[t] = ldf(bf1, t - 1536, F);
  else if (t < 2560) biasComb[t] = ldf(bf2, t - 2048, F);
  if (t < 512) {
    biasComb[2560 + t] = ldf(bha, t, F) + ldf(bhf, t, F);
    biasCat[t] = ldf(batt, t, F);       // p_att bias
    biasCat[512 + t] = 0.f;             // att_proj: no bias
    bfc_f[t] = ldf(bfc, t, F);
    walpha_f[t] = ldf(Walpha, t, F);
  }
  if (t < V_) blogit_f[t] = ldf(blogit, t, F);
}

// uniform-weight mean over a (196) of att_proj -> outc[b, seg*64 + lane]
__global__ __launch_bounds__(256) void att_apply_kernel(
    const float* __restrict__ alog, const u16* __restrict__ att_proj,
    float* __restrict__ outc)
{
  int b = blockIdx.x, seg = blockIdx.y, tid = threadIdx.x;
  __shared__ float sw[ATT_];
  __shared__ float rb[256];
  if (alog) {
    float l = (tid < ATT_) ? alog[b * ATT_ + tid] : -3.0e38f;
    rb[tid] = l; __syncthreads();
    for (int s = 128; s; s >>= 1) { if (tid < s) rb[tid] = fmaxf(rb[tid], rb[tid + s]); __syncthreads(); }
    float mx = rb[0]; __syncthreads();
    float e = (tid < ATT_) ? __expf(l - mx) : 0.f;
    rb[tid] = e; __syncthreads();
    for (int s = 128; s; s >>= 1) { if (tid < s) rb[tid] += rb[tid + s]; __syncthreads(); }
    float sum = rb[0]; __syncthreads();
    if (tid < ATT_) sw[tid] = e / sum;
  } else {
    if (tid < ATT_) sw[tid] = 1.f / (float)ATT_;
  }
  __syncthreads();
  int lane = tid & 63, g = tid >> 6;
  int col = seg * 64 + lane;
  float acc = 0.f;
  for (int a = g; a < ATT_; a += 4)
    acc += sw[a] * b2f(att_proj[(size_t)(b * ATT_ + a) * H_ + col]);
  rb[tid] = acc; __syncthreads();
  if (g == 0) outc[b * H_ + col] = rb[lane] + rb[64 + lane] + rb[128 + lane] + rb[192 + lane];
}

// in-place log_softmax over V=10000 per row of d_out (f32)
__global__ __launch_bounds__(256) void logsoftmax_kernel(float* __restrict__ out)
{
  __shared__ float vals[V_];
  __shared__ float rb[256];
  int row = blockIdx.x, tid = threadIdx.x;
  float* p = out + (size_t)row * V_;
  float mx = -3.0e38f;
  for (int c = tid * 4; c < V_; c += 1024) {
    float4 q = *(const float4*)(p + c);
    vals[c] = q.x; vals[c + 1] = q.y; vals[c + 2] = q.z; vals[c + 3] = q.w;
    mx = fmaxf(mx, fmaxf(fmaxf(q.x, q.y), fmaxf(q.z, q.w)));
  }
  rb[tid] = mx; __syncthreads();
  for (int s = 128; s; s >>= 1) { if (tid < s) rb[tid] = fmaxf(rb[tid], rb[tid + s]); __syncthreads(); }
  mx = rb[0]; __syncthreads();
  float sum = 0.f;
  for (int c = tid; c < V_; c += 256) sum += __expf(vals[c] - mx);
  rb[tid] = sum; __syncthreads();
  for (int s = 128; s; s >>= 1) { if (tid < s) rb[tid] += rb[tid + s]; __syncthreads(); }
  float lse = mx + __logf(rb[0]);
  for (int c = tid * 4; c < V_; c += 1024) {
    float4 q;
    q.x = vals[c] - lse; q.y = vals[c + 1] - lse;
    q.z = vals[c + 2] - lse; q.w = vals[c + 3] - lse;
    *(float4*)(p + c) = q;
  }
}

extern "C" void kernel_launch(void* const* d_in, const int* in_sizes, int n_in,
                              void* d_out, int out_size, void* d_ws, size_t ws_size,
                              hipStream_t stream)
{
  const int* word_idx   = (const int*)d_in[0];
  const int* father_idx = (const int*)d_in[1];
  const void* fc_feats  = d_in[2];
  const void* att_feats = d_in[3];
  const void* W_fc      = d_in[4];
  const void* b_fc      = d_in[5];
  const void* W_att     = d_in[6];
  const void* b_att     = d_in[7];
  const void* embed_tab = d_in[8];
  const void* weight_f1 = d_in[9];
  const void* bias_f1   = d_in[10];
  const void* weight_f2 = d_in[11];
  const void* bias_f2   = d_in[12];
  const void* weight_H  = d_in[13];
  const void* bias_H    = d_in[14];
  const void* weight_I  = d_in[15];
  const void* bias_I    = d_in[16];
  const void* W_ha      = d_in[17];
  const void* b_ha      = d_in[18];
  const void* W_hf      = d_in[19];
  const void* b_hf      = d_in[20];
  const void* W_alpha   = d_in[21];
  const void* b_alpha   = d_in[22];   // unused: softmax is shift-invariant
  const void* W_logit   = d_in[23];
  const void* b_logit   = d_in[24];
  (void)b_alpha;

  // ---- d_out (122.88 MB) hosts all dead-before-logits scratch -------------
  char* dob = (char*)d_out;
  size_t doff = 0;
  auto oalloc = [&](size_t bytes) -> char* {
    char* p = dob + doff;
    doff += (bytes + 255) & ~(size_t)255;
    return p;
  };
  u16*  p_att    = (u16*)oalloc((size_t)B_ * ATT_ * E_ * 2);    // 12.85 MB
  u16*  att_proj = (u16*)oalloc((size_t)B_ * ATT_ * H_ * 2);    // 12.85 MB
  u16*  att_bf16 = (u16*)oalloc((size_t)B_ * ATT_ * AF_ * 2);   // 51.38 MB
  float* Gx       = (float*)att_bf16;   // 31.46 MB alias: dead after att GEMM
  u16*  WstepX   = (u16*)oalloc((size_t)2560 * 1024 * 2);       //  5.24 MB
  u16*  Wcomb    = (u16*)oalloc((size_t)GB_N * 1024 * 2);       //  6.29 MB
  u16*  Wcat     = (u16*)oalloc((size_t)1024 * 2048 * 2);       //  4.19 MB
  u16*  XAll     = (u16*)oalloc((size_t)B_ * T_ * 1024 * 2);    //  6.29 MB
  float* c_states = (float*)oalloc((size_t)B_ * T_ * H_ * 4);   //  6.29 MB
  float* GbufA    = (float*)oalloc((size_t)2 * B_ * GB_N * 4);  //  1.57 MB
  float* GbufB    = (float*)oalloc((size_t)2 * B_ * GB_N * 4);  //  1.57 MB
  u16*  hcat     = (u16*)oalloc((size_t)B_ * 1024 * 2);         //  0.13 MB
  float* fc_emb   = (float*)oalloc((size_t)B_ * E_ * 4);
  float* att_meanp= (float*)oalloc((size_t)B_ * H_ * 4);
  float* biasComb = (float*)oalloc(GB_N * 4);
  float* biasCat  = (float*)oalloc(1024 * 4);
  float* bfc_f    = (float*)oalloc(512 * 4);
  float* walpha_f = (float*)oalloc(512 * 4);
  // total ~109 MB < 122.88 MB ✓

  // ---- only buffers LIVE during the final logits GEMM go in d_ws ----------
  char* ws = (char*)d_ws;
  size_t woff = 0;
  auto walloc = [&](size_t bytes) -> char* {
    char* p = ws + woff;
    woff += (bytes + 255) & ~(size_t)255;
    return p;
  };
  u16*  houts     = (u16*)walloc((size_t)B_ * T_ * H_ * 2);     // 3.15 MB
  float* blogit_f = (float*)walloc((size_t)V_ * 4);
  int*   flag     = (int*)walloc(256);
  int*   barws    = (int*)walloc(256);

  hipMemsetAsync(c_states, 0, (size_t)B_ * T_ * H_ * 4, stream);
  hipMemsetAsync(houts, 0, (size_t)B_ * T_ * H_ * 2, stream);
  hipMemsetAsync(barws, 0, 256, stream);

  detect_f32<<<1, 256, 0, stream>>>((const u16*)att_feats, flag);

  pack_wstep<<<4096, 256, 0, stream>>>(weight_H, weight_I, weight_f1, weight_f2,
                                       WstepX, Wcomb, flag);
  pack_whahf<<<2048, 256, 0, stream>>>(W_ha, W_hf, Wcomb, flag);
  pack_wcat<<<2048, 256, 0, stream>>>(W_att, weight_I, Wcat, flag);
  pack_attf<<<4096, 256, 0, stream>>>(att_feats, att_bf16, flag);
  pack_bias<<<40, 256, 0, stream>>>(bias_H, bias_I, bias_f1, bias_f2, b_ha, b_hf,
                                    b_att, b_fc, b_logit, W_alpha,
                                    biasComb, biasCat, bfc_f, blogit_f,
                                    walpha_f, flag);

  // fc_emb = fc_feats @ W_fc^T + b_fc  (f32 out)
  gemm_nt<float><<<dim3(1, 8, 1), 256, 0, stream>>>(
      fc_feats, FC_, 0, MD_DYN, W_fc, FC_, 0, MD_DYN,
      fc_emb, E_, E_, FC_, bfc_f, 0, flag);
  pack_xall<<<B_ * T_, 256, 0, stream>>>(fc_emb, embed_tab, word_idx, father_idx,
                                         XAll, flag);
  // FUSED: [p_att | att_proj] = att_bf16 @ Wcat^T (+biasCat), one A pass.
  // cols 0..511 -> p_att (b_att bias), 512..1023 -> att_proj (no bias).
  gemm_nt128<u16><<<dim3(8, B_ * ATT_ / 64), 512, 0, stream>>>(
      att_bf16, AF_, Wcat, 2048, p_att, att_proj, 512, AF_, biasCat);
  // Gx = XAll @ WstepX^T (x-half of all 48 step-GEMMs, hoisted; bias lives in
  // the per-step GEMM z0). OVERWRITES att_bf16 (dead after fused att GEMM).
  gemm_nt128<float><<<dim3(20, B_ * T_ / 64), 512, 0, stream>>>(
      XAll, 1024, WstepX, 1024, Gx, nullptr, 2560, 1024, nullptr);
  // att_mean contribution = mean_a att_proj
  att_apply_kernel<<<dim3(B_, 8), 256, 0, stream>>>(nullptr, att_proj, att_meanp);

  // Gbuf for step 0: h inputs zero -> z0 = bias, z1 = 0
  ginit<<<(B_ * GB_N) / 512, 512, 0, stream>>>(GbufA, biasComb);

  // ---- T=48 loop: ONE kernel per step (internal att->GEMM sync) -----------
  float* Gp = GbufA;
  float* Gn = GbufB;
  for (int i = 0; i < T_; ++i) {
    step_full<<<112, 512, 0, stream>>>(
        Gp, Gn, p_att, walpha_f, att_proj, att_meanp, Gx,
        c_states, houts, hcat, father_idx, Wcomb, biasComb,
        barws, 64 * (i + 1), i);
    float* t = Gp; Gp = Gn; Gn = t;
  }

  // logits = houts @ W_logit^T + b_logit -> d_out (f32), XCD-chunked tiles,
  // then in-place log_softmax.
  gemm_logit<<<48 * 160, 256, 0, stream>>>(houts, W_logit, (float*)d_out,
                                           blogit_f, flag);
  logsoftmax_kernel<<<B_ * T_, 256, 0, stream>>>((float*)d_out);
}